// Round 1
// baseline (819.407 us; speedup 1.0000x reference)
//
#include <hip/hip_runtime.h>

#define B_ 4
#define C_ 64
#define H_ 128
#define W_ 128
#define O_ 64
#define HW_ (H_*W_)
#define NOFF 18
#define CK_ 576

// ---------------- Kernel 1: offset conv (B,18,H,W) ----------------
// thread per output element; border handled by predicated loads
__global__ __launch_bounds__(256) void k_offset_conv(
    const float* __restrict__ x, const float* __restrict__ w_off,
    const float* __restrict__ b_off, float* __restrict__ offset)
{
    int idx = blockIdx.x * 256 + threadIdx.x;   // exactly 4*18*128*128 threads
    int j  = idx & (W_-1);
    int i  = (idx >> 7) & (H_-1);
    int oc = (idx >> 14) % NOFF;
    int b  = idx / (NOFF * HW_);
    float acc = b_off[oc];
    const float* xb = x + b * (C_*HW_);
    const float* wo = w_off + oc * CK_;
    bool ry0 = (i > 0), ry2 = (i < H_-1);
    bool cx0 = (j > 0), cx2 = (j < W_-1);
    for (int c = 0; c < C_; ++c) {
        const float* xc = xb + c*HW_ + i*W_ + j;
        const float* wc = wo + c*9;
        float v0 = (ry0 && cx0) ? xc[-W_-1] : 0.f;
        float v1 =  ry0         ? xc[-W_  ] : 0.f;
        float v2 = (ry0 && cx2) ? xc[-W_+1] : 0.f;
        float v3 =         cx0  ? xc[-1]    : 0.f;
        float v4 =                xc[0];
        float v5 =         cx2  ? xc[1]     : 0.f;
        float v6 = (ry2 && cx0) ? xc[W_-1]  : 0.f;
        float v7 =  ry2         ? xc[W_]    : 0.f;
        float v8 = (ry2 && cx2) ? xc[W_+1]  : 0.f;
        acc = fmaf(v0, wc[0], acc);
        acc = fmaf(v1, wc[1], acc);
        acc = fmaf(v2, wc[2], acc);
        acc = fmaf(v3, wc[3], acc);
        acc = fmaf(v4, wc[4], acc);
        acc = fmaf(v5, wc[5], acc);
        acc = fmaf(v6, wc[6], acc);
        acc = fmaf(v7, wc[7], acc);
        acc = fmaf(v8, wc[8], acc);
    }
    offset[idx] = acc;
}

// ---------------- Kernel 2: weight transpose (O,C,3,3) -> [k][c][o] ----------------
__global__ __launch_bounds__(256) void k_transpose_w(
    const float* __restrict__ w_dcn, float* __restrict__ w_t)
{
    int idx = blockIdx.x * 256 + threadIdx.x;   // exactly 64*576 = 36864 threads
    int ck = idx % CK_;
    int o  = idx / CK_;
    int c = ck / 9, k = ck % 9;
    w_t[(k*64 + c)*64 + o] = w_dcn[idx];
}

// ---------------- Kernel 3: deformable conv ----------------
// block = 256 threads: lane p = t&63 -> one of 64 consecutive j positions,
// wave g = t>>6 -> output-channel group of 16. Gathers coalesced over p.
__global__ __launch_bounds__(256) void k_deform(
    const float* __restrict__ x, const float* __restrict__ offset,
    const float* __restrict__ w_t, const float* __restrict__ b_dcn,
    float* __restrict__ out)
{
    int t = threadIdx.x;
    int p = t & 63;
    int g = t >> 6;
    int pos = blockIdx.x * 64 + p;      // 65536 positions total
    int j = pos & (W_-1);
    int i = (pos >> 7) & (H_-1);
    int b = pos >> 14;

    float acc[16];
    #pragma unroll
    for (int q = 0; q < 16; ++q) acc[q] = b_dcn[g*16 + q];

    const float* xb   = x + b * (C_*HW_);
    const float* offb = offset + b * (NOFF*HW_) + i*W_ + j;

    for (int k = 0; k < 9; ++k) {
        float oy = offb[(2*k  )*HW_];
        float ox = offb[(2*k+1)*HW_];
        float py = (float)(i - 1 + k/3) + oy;
        float px = (float)(j - 1 + k%3) + ox;
        float y0f = floorf(py), x0f = floorf(px);
        float dy = py - y0f, dx = px - x0f;
        int y0 = (int)y0f, x0 = (int)x0f;
        int y1 = y0 + 1,   x1 = x0 + 1;
        bool vy0 = (y0 >= 0) & (y0 < H_);
        bool vy1 = (y1 >= 0) & (y1 < H_);
        bool vx0 = (x0 >= 0) & (x0 < W_);
        bool vx1 = (x1 >= 0) & (x1 < W_);
        int yc0 = min(max(y0, 0), H_-1), yc1 = min(max(y1, 0), H_-1);
        int xc0 = min(max(x0, 0), W_-1), xc1 = min(max(x1, 0), W_-1);
        // fold validity into bilinear weights (branchless c-loop)
        float w00 = (1.f-dy)*(1.f-dx) * ((vy0 && vx0) ? 1.f : 0.f);
        float w01 = (1.f-dy)*dx       * ((vy0 && vx1) ? 1.f : 0.f);
        float w10 = dy*(1.f-dx)       * ((vy1 && vx0) ? 1.f : 0.f);
        float w11 = dy*dx             * ((vy1 && vx1) ? 1.f : 0.f);
        int r00 = yc0*W_ + xc0, r01 = yc0*W_ + xc1;
        int r10 = yc1*W_ + xc0, r11 = yc1*W_ + xc1;
        const float* wkbase = w_t + k*64*64 + g*16;
        #pragma unroll 2
        for (int c = 0; c < C_; ++c) {
            const float* bp = xb + c*HW_;
            float s = bp[r00]*w00 + bp[r01]*w01 + bp[r10]*w10 + bp[r11]*w11;
            const float4* w4 = (const float4*)(wkbase + c*64);
            float4 wa = w4[0], wb = w4[1], wc = w4[2], wd = w4[3];
            acc[ 0] = fmaf(s, wa.x, acc[ 0]);
            acc[ 1] = fmaf(s, wa.y, acc[ 1]);
            acc[ 2] = fmaf(s, wa.z, acc[ 2]);
            acc[ 3] = fmaf(s, wa.w, acc[ 3]);
            acc[ 4] = fmaf(s, wb.x, acc[ 4]);
            acc[ 5] = fmaf(s, wb.y, acc[ 5]);
            acc[ 6] = fmaf(s, wb.z, acc[ 6]);
            acc[ 7] = fmaf(s, wb.w, acc[ 7]);
            acc[ 8] = fmaf(s, wc.x, acc[ 8]);
            acc[ 9] = fmaf(s, wc.y, acc[ 9]);
            acc[10] = fmaf(s, wc.z, acc[10]);
            acc[11] = fmaf(s, wc.w, acc[11]);
            acc[12] = fmaf(s, wd.x, acc[12]);
            acc[13] = fmaf(s, wd.y, acc[13]);
            acc[14] = fmaf(s, wd.z, acc[14]);
            acc[15] = fmaf(s, wd.w, acc[15]);
        }
    }
    int obase = ((b*O_ + g*16)*H_ + i)*W_ + j;
    #pragma unroll
    for (int q = 0; q < 16; ++q) out[obase + q*HW_] = acc[q];
}

extern "C" void kernel_launch(void* const* d_in, const int* in_sizes, int n_in,
                              void* d_out, int out_size, void* d_ws, size_t ws_size,
                              hipStream_t stream) {
    const float* x     = (const float*)d_in[0];
    const float* w_off = (const float*)d_in[1];
    const float* b_off = (const float*)d_in[2];
    const float* w_dcn = (const float*)d_in[3];
    const float* b_dcn = (const float*)d_in[4];
    float* out = (float*)d_out;

    float* offset = (float*)d_ws;                    // 4*18*128*128 = 1,179,648 floats
    float* w_t    = offset + (size_t)B_*NOFF*HW_;    // 36,864 floats

    {   // offset conv: 1,179,648 threads
        int total = B_*NOFF*HW_;
        k_offset_conv<<<total/256, 256, 0, stream>>>(x, w_off, b_off, offset);
    }
    {   // weight transpose: 36,864 threads
        int total = O_*CK_;
        k_transpose_w<<<total/256, 256, 0, stream>>>(w_dcn, w_t);
    }
    {   // deform: 1024 blocks x 256
        k_deform<<<(B_*HW_)/64, 256, 0, stream>>>(x, offset, w_t, b_dcn, out);
    }
}

// Round 2
// 522.093 us; speedup vs baseline: 1.5695x; 1.5695x over previous
//
#include <hip/hip_runtime.h>

#define B_ 4
#define C_ 64
#define H_ 128
#define W_ 128
#define O_ 64
#define HW_ (H_*W_)
#define NOFF 18

// ws layout (floats):
//   x_t    : B*HW*C      = 4,194,304   (NHWC: x_t[b][i][j][c])
//   offset : B*18*HW     = 1,179,648   ([b][oc][i][j])
//   w_t2   : 9*4*64*16   = 36,864      (w_t2[((k*4+g)*64+c)*16+q] = w_dcn[g*16+q][c][k])
//   w_off_t: 9*16*18*4   = 10,368      (w_off_t[((k*16+c4)*18+oc)*4+cl] = w_off[oc][c4*4+cl][k])

// ---------------- Kernel 1: NCHW -> NHWC transpose of x ----------------
__global__ __launch_bounds__(256) void k_transpose_x(
    const float* __restrict__ x, float* __restrict__ x_t)
{
    __shared__ float tile[64][65];
    int t = threadIdx.x;
    int base = blockIdx.x * 64;           // global pos base (b*HW + p), 64-aligned
    int b = base >> 14;
    int pin = base & (HW_-1);
    // load 64 ch x 64 pos, coalesced over pos
    #pragma unroll
    for (int it = 0; it < 16; ++it) {
        int c = it*4 + (t >> 6);
        int p = t & 63;
        tile[c][p] = x[b*(C_*HW_) + c*HW_ + pin + p];
    }
    __syncthreads();
    // store coalesced over c
    #pragma unroll
    for (int it = 0; it < 16; ++it) {
        int p = it*4 + (t >> 6);
        int c = t & 63;
        x_t[(size_t)(base + p)*64 + c] = tile[c][p];
    }
}

// ---------------- Kernel 2: weight relayouts ----------------
__global__ __launch_bounds__(256) void k_transpose_w(
    const float* __restrict__ w_dcn, const float* __restrict__ w_off,
    float* __restrict__ w_t2, float* __restrict__ w_off_t)
{
    int idx = blockIdx.x * 256 + threadIdx.x;
    if (idx < 36864) {
        int q = idx & 15;
        int c = (idx >> 4) & 63;
        int g = (idx >> 10) & 3;
        int k = idx >> 12;
        w_t2[idx] = w_dcn[(g*16+q)*576 + c*9 + k];
    } else if (idx < 36864 + 10368) {
        int r = idx - 36864;
        int cl = r & 3;
        int oc = (r >> 2) % 18;
        int rem = r / 72;
        int c4 = rem & 15;
        int k  = rem >> 4;
        w_off_t[r] = w_off[oc*576 + (c4*4+cl)*9 + k];
    }
}

// ---------------- Kernel 3: offset conv ----------------
// thread = one output position, computes all 18 offset channels.
// x in NHWC: per tap one float4 (4 channels) per c4 iteration; weights uniform -> s_load.
__global__ __launch_bounds__(256) void k_offset_conv(
    const float* __restrict__ x_t, const float* __restrict__ w_off_t,
    const float* __restrict__ b_off, float* __restrict__ offset)
{
    int gp = blockIdx.x * 256 + threadIdx.x;     // 65536 threads
    int j = gp & (W_-1);
    int i = (gp >> 7) & (H_-1);
    int b = gp >> 14;

    float acc[18];
    #pragma unroll
    for (int m = 0; m < 18; ++m) acc[m] = b_off[m];

    const float* xb = x_t + (size_t)b * (HW_*64);

    for (int ky = 0; ky < 3; ++ky) {
        for (int kx = 0; kx < 3; ++kx) {
            int k = ky*3 + kx;
            int ii = i - 1 + ky;
            int jj = j - 1 + kx;
            bool valid = (ii >= 0) & (ii < H_) & (jj >= 0) & (jj < W_);
            int iic = min(max(ii,0),H_-1), jjc = min(max(jj,0),W_-1);
            float sc = valid ? 1.f : 0.f;
            const float4* px = (const float4*)(xb + (size_t)(iic*W_ + jjc)*64);
            const float* wk = w_off_t + k*(16*72);
            #pragma unroll 2
            for (int c4 = 0; c4 < 16; ++c4) {
                float4 v = px[c4];
                v.x *= sc; v.y *= sc; v.z *= sc; v.w *= sc;
                const float* wp = wk + c4*72;
                #pragma unroll
                for (int oc = 0; oc < 18; ++oc) {
                    float a = acc[oc];
                    a = fmaf(v.x, wp[oc*4+0], a);
                    a = fmaf(v.y, wp[oc*4+1], a);
                    a = fmaf(v.z, wp[oc*4+2], a);
                    a = fmaf(v.w, wp[oc*4+3], a);
                    acc[oc] = a;
                }
            }
        }
    }
    int obase = b*(NOFF*HW_) + i*W_ + j;
    #pragma unroll
    for (int oc = 0; oc < 18; ++oc) offset[obase + oc*HW_] = acc[oc];
}

// ---------------- Kernel 4: deformable conv ----------------
// block = 256: lane = one of 64 consecutive positions, wave g = 16-o-channel group.
// NHWC x: each corner read is a per-lane float4 (4 channels). Weights uniform (s_load).
__global__ __launch_bounds__(256) void k_deform(
    const float* __restrict__ x_t, const float* __restrict__ offset,
    const float* __restrict__ w_t2, const float* __restrict__ b_dcn,
    float* __restrict__ out)
{
    int t = threadIdx.x;
    int lane = t & 63;
    int gg = __builtin_amdgcn_readfirstlane(t >> 6);   // wave-uniform o-group
    int pos = blockIdx.x * 64 + lane;
    int j = pos & (W_-1);
    int i = (pos >> 7) & (H_-1);
    int b = pos >> 14;

    float acc[16];
    #pragma unroll
    for (int q = 0; q < 16; ++q) acc[q] = b_dcn[gg*16 + q];

    const float* xb   = x_t + (size_t)b * (HW_*64);
    const float* offb = offset + b*(NOFF*HW_) + i*W_ + j;

    // hoist all 18 offsets (coalesced dword loads)
    float offv[18];
    #pragma unroll
    for (int m = 0; m < 18; ++m) offv[m] = offb[m*HW_];

    for (int ky = 0; ky < 3; ++ky) {
        for (int kx = 0; kx < 3; ++kx) {
            int k = ky*3 + kx;
            float oy = offv[2*k];
            float ox = offv[2*k+1];
            float py = (float)(i - 1 + ky) + oy;
            float px = (float)(j - 1 + kx) + ox;
            float y0f = floorf(py), x0f = floorf(px);
            float dy = py - y0f, dx = px - x0f;
            int y0 = (int)y0f, x0 = (int)x0f;
            int y1 = y0 + 1,   x1 = x0 + 1;
            bool vy0 = (y0 >= 0) & (y0 < H_);
            bool vy1 = (y1 >= 0) & (y1 < H_);
            bool vx0 = (x0 >= 0) & (x0 < W_);
            bool vx1 = (x1 >= 0) & (x1 < W_);
            int yc0 = min(max(y0,0),H_-1), yc1 = min(max(y1,0),H_-1);
            int xc0 = min(max(x0,0),W_-1), xc1 = min(max(x1,0),W_-1);
            float w00 = (1.f-dy)*(1.f-dx) * ((vy0 && vx0) ? 1.f : 0.f);
            float w01 = (1.f-dy)*dx       * ((vy0 && vx1) ? 1.f : 0.f);
            float w10 = dy*(1.f-dx)       * ((vy1 && vx0) ? 1.f : 0.f);
            float w11 = dy*dx             * ((vy1 && vx1) ? 1.f : 0.f);
            const float4* p00 = (const float4*)(xb + (size_t)(yc0*W_ + xc0)*64);
            const float4* p01 = (const float4*)(xb + (size_t)(yc0*W_ + xc1)*64);
            const float4* p10 = (const float4*)(xb + (size_t)(yc1*W_ + xc0)*64);
            const float4* p11 = (const float4*)(xb + (size_t)(yc1*W_ + xc1)*64);
            const float* wkg = w_t2 + (k*4 + gg)*1024;   // 64c x 16o, uniform
            #pragma unroll 4
            for (int c4 = 0; c4 < 16; ++c4) {
                float4 f00 = p00[c4], f01 = p01[c4], f10 = p10[c4], f11 = p11[c4];
                float4 s;
                s.x = fmaf(f00.x,w00, fmaf(f01.x,w01, fmaf(f10.x,w10, f11.x*w11)));
                s.y = fmaf(f00.y,w00, fmaf(f01.y,w01, fmaf(f10.y,w10, f11.y*w11)));
                s.z = fmaf(f00.z,w00, fmaf(f01.z,w01, fmaf(f10.z,w10, f11.z*w11)));
                s.w = fmaf(f00.w,w00, fmaf(f01.w,w01, fmaf(f10.w,w10, f11.w*w11)));
                const float* wp = wkg + c4*64;           // 64 consecutive uniform floats
                #pragma unroll
                for (int q = 0; q < 16; ++q) acc[q] = fmaf(s.x, wp[q],    acc[q]);
                #pragma unroll
                for (int q = 0; q < 16; ++q) acc[q] = fmaf(s.y, wp[16+q], acc[q]);
                #pragma unroll
                for (int q = 0; q < 16; ++q) acc[q] = fmaf(s.z, wp[32+q], acc[q]);
                #pragma unroll
                for (int q = 0; q < 16; ++q) acc[q] = fmaf(s.w, wp[48+q], acc[q]);
            }
        }
    }
    int obase = ((b*O_ + gg*16)*H_ + i)*W_ + j;
    #pragma unroll
    for (int q = 0; q < 16; ++q) out[obase + q*HW_] = acc[q];
}

extern "C" void kernel_launch(void* const* d_in, const int* in_sizes, int n_in,
                              void* d_out, int out_size, void* d_ws, size_t ws_size,
                              hipStream_t stream) {
    const float* x     = (const float*)d_in[0];
    const float* w_off = (const float*)d_in[1];
    const float* b_off = (const float*)d_in[2];
    const float* w_dcn = (const float*)d_in[3];
    const float* b_dcn = (const float*)d_in[4];
    float* out = (float*)d_out;

    float* x_t     = (float*)d_ws;                         // 4,194,304
    float* offset  = x_t + (size_t)B_*HW_*64;              // 1,179,648
    float* w_t2    = offset + (size_t)B_*NOFF*HW_;         // 36,864
    float* w_off_t = w_t2 + 36864;                         // 10,368

    k_transpose_x<<<(B_*HW_)/64, 256, 0, stream>>>(x, x_t);
    k_transpose_w<<<(36864 + 10368 + 255)/256, 256, 0, stream>>>(w_dcn, w_off, w_t2, w_off_t);
    k_offset_conv<<<(B_*HW_)/256, 256, 0, stream>>>(x_t, w_off_t, b_off, offset);
    k_deform<<<(B_*HW_)/64, 256, 0, stream>>>(x_t, offset, w_t2, b_dcn, out);
}

// Round 3
// 141.343 us; speedup vs baseline: 5.7973x; 3.6938x over previous
//
#include <hip/hip_runtime.h>
#include <hip/hip_fp16.h>

#define B_ 4
#define H_ 128
#define W_ 128
#define HW_ 16384
#define O_ 64

typedef _Float16 half8 __attribute__((ext_vector_type(8)));
typedef float floatx4 __attribute__((ext_vector_type(4)));

// ws layout (bytes):
//   x_h : f16 NHWC [4][128][128][64]           = 8,388,608
//   W2h : f16 [64 o][576 k] (k = tap*64+c)     =    73,728
//   W0h : f16 [32 oc][576 k] (rows 18..31 = 0) =    36,864

// ---------- prep 1: x NCHW f32 -> NHWC f16 ----------
__global__ __launch_bounds__(256) void k_prep_x(
    const float* __restrict__ x, __half* __restrict__ x_h)
{
    __shared__ float tile[64][65];
    int t = threadIdx.x;
    int base = blockIdx.x * 64;
    int b = base >> 14;
    int pin = base & (HW_-1);
    #pragma unroll
    for (int it = 0; it < 16; ++it) {
        int c = it*4 + (t >> 6);
        int p = t & 63;
        tile[c][p] = x[b*(64*HW_) + c*HW_ + pin + p];
    }
    __syncthreads();
    #pragma unroll
    for (int it = 0; it < 8; ++it) {
        int p  = it*8 + (t >> 5);
        int c2 = (t & 31) * 2;
        __half2 h2 = __floats2half2_rn(tile[c2][p], tile[c2+1][p]);
        *(__half2*)(x_h + (size_t)(base + p)*64 + c2) = h2;
    }
}

// ---------- prep 2: weights -> f16, k-major (k = tap*64 + c) ----------
__global__ __launch_bounds__(256) void k_prep_w(
    const float* __restrict__ w_dcn, const float* __restrict__ w_off,
    __half* __restrict__ W2h, __half* __restrict__ W0h)
{
    int idx = blockIdx.x*256 + threadIdx.x;
    if (idx < 36864) {
        int o = idx / 576; int r = idx % 576; int tap = r >> 6; int c = r & 63;
        W2h[idx] = __float2half(w_dcn[o*576 + c*9 + tap]);
    } else if (idx < 36864 + 18432) {
        int i2 = idx - 36864;
        int oc = i2 / 576; int r = i2 % 576; int tap = r >> 6; int c = r & 63;
        W0h[i2] = (oc < 18) ? __float2half(w_off[oc*576 + c*9 + tap])
                            : __float2half(0.f);
    }
}

// ---------- fused: offset conv (MFMA) + deform sample + deform GEMM (MFMA) ----------
// block = 256 thr = 4 waves, handles 64 consecutive positions (one half-row).
// lane = channel(-pair) for sampling; MFMA does the cross-lane O-reduction.
__global__ __launch_bounds__(256, 4) void k_fused(
    const __half* __restrict__ x_h, const _Float16* __restrict__ W2h,
    const _Float16* __restrict__ W0h, const float* __restrict__ b_off,
    const float* __restrict__ b_dcn, float* __restrict__ out)
{
    // S: [2][64 pos][72 f16] double-buffered sample tile (stride 72 -> bank-balanced
    // b128 A-frag reads, 2-way-free b32 writes). offL: [64 pos][20 f32] offsets.
    __shared__ __attribute__((aligned(16))) char smem[18432 + 5120];
    _Float16* S    = (_Float16*)smem;
    float*    offL = (float*)(smem + 18432);

    int t = threadIdx.x;
    int lane = t & 63;
    int w = __builtin_amdgcn_readfirstlane(t >> 6);
    int m = lane & 15, q = lane >> 4;           // MFMA fragment coords
    int halfid = lane >> 5, cp = lane & 31;     // sampling: 2 positions/iter, 32 ch-pairs

    // XCD swizzle: each XCD gets a contiguous half-image (~1 MB, L2-resident)
    int bid  = blockIdx.x;
    int orig = (bid & 7)*128 + (bid >> 3);
    int base = orig * 64;
    int b  = base >> 14;
    int p0 = base & (HW_-1);
    int i  = p0 >> 7;
    int j0 = p0 & 127;

    const __half* xb = x_h + (size_t)b * (HW_*64);

    // ================= Phase A: offset conv =================
    floatx4 accA[2];
    #pragma unroll
    for (int h = 0; h < 2; ++h) accA[h] = (floatx4){0.f,0.f,0.f,0.f};

    for (int tap = 0; tap < 9; ++tap) {
        int kh = tap/3, kw = tap - (tap/3)*3;
        _Float16* Sb = S + (tap & 1)*4608;
        int ii = i - 1 + kh;
        bool vy = (ii >= 0) && (ii < H_);
        int iic = min(max(ii,0),H_-1);
        #pragma unroll 4
        for (int iter = 0; iter < 8; ++iter) {
            int p  = (w<<4) + iter + (halfid<<3);
            int jj = j0 + p - 1 + kw;
            bool valid = vy && (jj >= 0) && (jj < W_);
            int jjc = min(max(jj,0),W_-1);
            unsigned v = *(const unsigned*)(xb + ((iic<<7) + jjc)*64 + 2*cp);
            v = valid ? v : 0u;
            *(unsigned*)(Sb + p*72 + 2*cp) = v;
        }
        __syncthreads();
        #pragma unroll
        for (int ks = 0; ks < 2; ++ks) {
            half8 a = *(const half8*)(Sb + (w*16 + m)*72 + ks*32 + q*8);
            #pragma unroll
            for (int h = 0; h < 2; ++h) {
                half8 bf = *(const half8*)(W0h + (h*16 + m)*576 + tap*64 + ks*32 + q*8);
                accA[h] = __builtin_amdgcn_mfma_f32_16x16x32_f16(a, bf, accA[h], 0, 0, 0);
            }
        }
        // no second barrier: next tap writes the other S buffer
    }
    // epilogue A: D layout col=lane&15 (=oc), row=q*4+r (=pos in tile w)
    #pragma unroll
    for (int h = 0; h < 2; ++h) {
        int oc = h*16 + m;
        if (oc < 18) {
            float bo = b_off[oc];
            #pragma unroll
            for (int r = 0; r < 4; ++r) {
                int pos = w*16 + q*4 + r;
                offL[pos*20 + oc] = accA[h][r] + bo;
            }
        }
    }
    __syncthreads();

    // ================= Phase B: deformable conv =================
    floatx4 acc[4];
    #pragma unroll
    for (int pt = 0; pt < 4; ++pt) acc[pt] = (floatx4){0.f,0.f,0.f,0.f};

    for (int tap = 0; tap < 9; ++tap) {
        int kh = tap/3, kw = tap - (tap/3)*3;
        _Float16* Sb = S + (tap & 1)*4608;
        #pragma unroll 2
        for (int iter = 0; iter < 8; ++iter) {
            int p = (w<<4) + iter + (halfid<<3);
            int j = j0 + p;
            float2 o2 = *(const float2*)(offL + p*20 + 2*tap);
            float py = (float)(i - 1 + kh) + o2.x;
            float px = (float)(j - 1 + kw) + o2.y;
            float y0f = floorf(py), x0f = floorf(px);
            float dy = py - y0f, dx = px - x0f;
            int y0 = (int)y0f, x0i = (int)x0f;
            int y1 = y0 + 1,  x1 = x0i + 1;
            bool vy0 = (y0>=0)&(y0<H_),  vy1 = (y1>=0)&(y1<H_);
            bool vx0 = (x0i>=0)&(x0i<W_), vx1 = (x1>=0)&(x1<W_);
            int yc0 = min(max(y0,0),H_-1),  yc1 = min(max(y1,0),H_-1);
            int xc0 = min(max(x0i,0),W_-1), xc1 = min(max(x1,0),W_-1);
            float w00 = (1.f-dy)*(1.f-dx) * ((vy0&&vx0)?1.f:0.f);
            float w01 = (1.f-dy)*dx       * ((vy0&&vx1)?1.f:0.f);
            float w10 = dy*(1.f-dx)       * ((vy1&&vx0)?1.f:0.f);
            float w11 = dy*dx             * ((vy1&&vx1)?1.f:0.f);
            const __half* pb = xb + 2*cp;
            __half2 v00 = *(const __half2*)(pb + ((yc0<<7)+xc0)*64);
            __half2 v01 = *(const __half2*)(pb + ((yc0<<7)+xc1)*64);
            __half2 v10 = *(const __half2*)(pb + ((yc1<<7)+xc0)*64);
            __half2 v11 = *(const __half2*)(pb + ((yc1<<7)+xc1)*64);
            float slo = __low2float(v00)*w00 + __low2float(v01)*w01
                      + __low2float(v10)*w10 + __low2float(v11)*w11;
            float shi = __high2float(v00)*w00 + __high2float(v01)*w01
                      + __high2float(v10)*w10 + __high2float(v11)*w11;
            *(__half2*)(Sb + p*72 + 2*cp) = __floats2half2_rn(slo, shi);
        }
        __syncthreads();
        #pragma unroll
        for (int ks = 0; ks < 2; ++ks) {
            half8 bf = *(const half8*)(W2h + (w*16 + m)*576 + tap*64 + ks*32 + q*8);
            #pragma unroll
            for (int pt = 0; pt < 4; ++pt) {
                half8 a = *(const half8*)(Sb + (pt*16 + m)*72 + ks*32 + q*8);
                acc[pt] = __builtin_amdgcn_mfma_f32_16x16x32_f16(a, bf, acc[pt], 0, 0, 0);
            }
        }
    }
    __syncthreads();   // protect smem reuse below against last GEMM reads

    // epilogue B: LDS transpose -> coalesced NCHW stores
    float* E = (float*)smem;   // [64 pos][66]
    #pragma unroll
    for (int pt = 0; pt < 4; ++pt) {
        #pragma unroll
        for (int r = 0; r < 4; ++r)
            E[(pt*16 + q*4 + r)*66 + w*16 + m] = acc[pt][r];
    }
    __syncthreads();
    int obase = (b*64)*HW_ + (i<<7) + j0;
    #pragma unroll
    for (int rep = 0; rep < 16; ++rep) {
        int o = rep*4 + w;
        out[obase + o*HW_ + lane] = E[lane*66 + o] + b_dcn[o];
    }
}

extern "C" void kernel_launch(void* const* d_in, const int* in_sizes, int n_in,
                              void* d_out, int out_size, void* d_ws, size_t ws_size,
                              hipStream_t stream) {
    const float* x     = (const float*)d_in[0];
    const float* w_off = (const float*)d_in[1];
    const float* b_off = (const float*)d_in[2];
    const float* w_dcn = (const float*)d_in[3];
    const float* b_dcn = (const float*)d_in[4];
    float* out = (float*)d_out;

    __half* x_h = (__half*)d_ws;                           // 8,388,608 B
    __half* W2h = (__half*)((char*)d_ws + 8388608);        //    73,728 B
    __half* W0h = (__half*)((char*)d_ws + 8388608 + 73728);//    36,864 B

    k_prep_x<<<(B_*HW_)/64, 256, 0, stream>>>(x, x_h);
    k_prep_w<<<216, 256, 0, stream>>>(w_dcn, w_off, W2h, W0h);
    k_fused<<<(B_*HW_)/64, 256, 0, stream>>>(x_h, (const _Float16*)W2h,
                                             (const _Float16*)W0h, b_off, b_dcn, out);
}

// Round 4
// 130.643 us; speedup vs baseline: 6.2721x; 1.0819x over previous
//
#include <hip/hip_runtime.h>
#include <hip/hip_fp16.h>

#define B_ 4
#define H_ 128
#define W_ 128
#define HW_ 16384

typedef _Float16 half8 __attribute__((ext_vector_type(8)));
typedef float floatx4 __attribute__((ext_vector_type(4)));

// ws layout (bytes):
//   x_h : f16 NHWC [4][128][128][64]           = 8,388,608
//   W2h : f16 [64 o][576 k] (k = tap*64+c)     =    73,728
//   W0h : f16 [32 oc][576 k] (rows 18..31 = 0) =    36,864

// ---------------- prep (merged): x NCHW f32 -> NHWC f16 + weights ----------------
__global__ __launch_bounds__(256) void k_prep(
    const float* __restrict__ x, const float* __restrict__ w_dcn,
    const float* __restrict__ w_off, __half* __restrict__ x_h,
    __half* __restrict__ W2h, __half* __restrict__ W0h)
{
    int bid = blockIdx.x;
    int t = threadIdx.x;
    if (bid < 1024) {
        __shared__ float tile[64][65];
        int base = bid * 64;
        int b = base >> 14;
        int pin = base & (HW_-1);
        #pragma unroll
        for (int it = 0; it < 16; ++it) {
            int c = it*4 + (t >> 6);
            int p = t & 63;
            tile[c][p] = x[b*(64*HW_) + c*HW_ + pin + p];
        }
        __syncthreads();
        #pragma unroll
        for (int it = 0; it < 4; ++it) {
            int p  = it*16 + (t >> 4);
            int c4 = (t & 15) * 4;
            __half2 lo = __floats2half2_rn(tile[c4][p],   tile[c4+1][p]);
            __half2 hi = __floats2half2_rn(tile[c4+2][p], tile[c4+3][p]);
            float2 v;
            v.x = *(float*)&lo; v.y = *(float*)&hi;
            *(float2*)(x_h + (size_t)(base+p)*64 + c4) = v;
        }
    } else {
        int idx = (bid - 1024)*256 + t;   // 55296 = 36864 + 18432
        if (idx < 36864) {
            int o = idx / 576; int r = idx % 576; int tap = r >> 6; int c = r & 63;
            W2h[idx] = __float2half(w_dcn[o*576 + c*9 + tap]);
        } else {
            int i2 = idx - 36864;
            int oc = i2 / 576; int r = i2 % 576; int tap = r >> 6; int c = r & 63;
            W0h[i2] = (oc < 18) ? __float2half(w_off[oc*576 + c*9 + tap])
                                : __float2half(0.f);
        }
    }
}

// ---------------- fused: offset conv (MFMA) + descriptor build + sample + GEMM ----
// block = 256 thr = 4 waves, 64 consecutive positions (half row, i uniform).
__global__ __launch_bounds__(256, 4) void k_fused(
    const __half* __restrict__ x_hg, const _Float16* __restrict__ W2h,
    const _Float16* __restrict__ W0h, const float* __restrict__ b_off,
    const float* __restrict__ b_dcn, float* __restrict__ out)
{
    // S    : [2][64 pos][72 f16]  = 18432 B (double-buffered sample tile)
    // offL : [64 pos][20 f32]     =  5120 B
    // dPix : [576][2 u32]         =  4608 B (4 packed u16 pixel ids)
    // dW   : [576][4 half2]       =  9216 B (bilinear weights, replicated)
    __shared__ __attribute__((aligned(16))) char smem[37376];
    _Float16* S    = (_Float16*)smem;
    float*    offL = (float*)(smem + 18432);
    unsigned* dPix = (unsigned*)(smem + 23552);
    __half2*  dW   = (__half2*)(smem + 28160);

    int t = threadIdx.x;
    int lane = t & 63;
    int w = __builtin_amdgcn_readfirstlane(t >> 6);
    int m = lane & 15, q = lane >> 4;       // MFMA frag coords; also (chan-quad, pos-sub)

    // XCD swizzle: contiguous half-image per XCD
    int bid  = blockIdx.x;
    int orig = (bid & 7)*128 + (bid >> 3);
    int base = orig * 64;
    int b  = base >> 14;
    int p0 = base & (HW_-1);
    int i  = p0 >> 7;
    int j0 = p0 & 127;

    const _Float16* xb = (const _Float16*)x_hg + (size_t)b * (HW_*64);

    // ================= Phase A: offset conv, direct-global A-frags =================
    floatx4 accA[2];
    #pragma unroll
    for (int h = 0; h < 2; ++h) accA[h] = (floatx4){0.f,0.f,0.f,0.f};

    const half8 hz = {0,0,0,0,0,0,0,0};
    int pcol = w*16 + m;                    // this lane's position row in the A tile
    #pragma unroll
    for (int tap = 0; tap < 9; ++tap) {
        int kh = tap/3, kw = tap - (tap/3)*3;
        int ii = i - 1 + kh;
        bool vy = (ii >= 0) && (ii < H_);
        int iic = min(max(ii,0),H_-1);
        int jj = j0 + pcol - 1 + kw;
        bool valid = vy && (jj >= 0) && (jj < W_);
        int jjc = min(max(jj,0),W_-1);
        const half8* ap = (const half8*)(xb + ((iic<<7)+jjc)*64 + q*8);
        half8 a0 = ap[0];      // channels q*8 .. q*8+7        (ks=0)
        half8 a1 = ap[4];      // channels 32+q*8 .. 32+q*8+7  (ks=1)
        a0 = valid ? a0 : hz;
        a1 = valid ? a1 : hz;
        #pragma unroll
        for (int h = 0; h < 2; ++h) {
            const half8* bp = (const half8*)(W0h + (h*16+m)*576 + tap*64 + q*8);
            accA[h] = __builtin_amdgcn_mfma_f32_16x16x32_f16(a0, bp[0], accA[h], 0, 0, 0);
            accA[h] = __builtin_amdgcn_mfma_f32_16x16x32_f16(a1, bp[4], accA[h], 0, 0, 0);
        }
    }
    // epilogue A: D layout col=lane&15 (=oc), row=q*4+r (=pos within wave tile)
    #pragma unroll
    for (int h = 0; h < 2; ++h) {
        int oc = h*16 + m;
        if (oc < 18) {
            float bo = b_off[oc];
            #pragma unroll
            for (int r = 0; r < 4; ++r) {
                int pos = w*16 + q*4 + r;
                offL[pos*20 + oc] = accA[h][r] + bo;
            }
        }
    }
    __syncthreads();

    // ================= descriptor build: one per (pos, tap) =================
    #pragma unroll
    for (int e = 0; e < 3; ++e) {
        int idx = e*256 + t;
        if (idx < 576) {
            int pos = idx / 9;
            int tap = idx - pos*9;
            int kh = tap/3, kw = tap - (tap/3)*3;
            float2 o2 = *(const float2*)(offL + pos*20 + 2*tap);
            float py = (float)(i - 1 + kh) + o2.x;
            float px = (float)(j0 + pos - 1 + kw) + o2.y;
            float y0f = floorf(py), x0f = floorf(px);
            float dy = py - y0f, dx = px - x0f;
            int y0 = (int)y0f, x0i = (int)x0f;
            int y1 = y0 + 1,  x1 = x0i + 1;
            bool vy0 = (y0>=0)&(y0<H_),   vy1 = (y1>=0)&(y1<H_);
            bool vx0 = (x0i>=0)&(x0i<W_), vx1 = (x1>=0)&(x1<W_);
            int yc0 = min(max(y0,0),H_-1),  yc1 = min(max(y1,0),H_-1);
            int xc0 = min(max(x0i,0),W_-1), xc1 = min(max(x1,0),W_-1);
            float w00 = (1.f-dy)*(1.f-dx) * ((vy0&&vx0)?1.f:0.f);
            float w01 = (1.f-dy)*dx       * ((vy0&&vx1)?1.f:0.f);
            float w10 = dy*(1.f-dx)       * ((vy1&&vx0)?1.f:0.f);
            float w11 = dy*dx             * ((vy1&&vx1)?1.f:0.f);
            dPix[idx*2]   = (unsigned)((yc0<<7)+xc0) | ((unsigned)((yc0<<7)+xc1) << 16);
            dPix[idx*2+1] = (unsigned)((yc1<<7)+xc0) | ((unsigned)((yc1<<7)+xc1) << 16);
            __half2 h00 = __floats2half2_rn(w00, w00);
            __half2 h01 = __floats2half2_rn(w01, w01);
            __half2 h10 = __floats2half2_rn(w10, w10);
            __half2 h11 = __floats2half2_rn(w11, w11);
            float4 wv;
            wv.x = *(float*)&h00; wv.y = *(float*)&h01;
            wv.z = *(float*)&h10; wv.w = *(float*)&h11;
            *(float4*)(dW + idx*4) = wv;
        }
    }
    __syncthreads();

    // ================= Phase B: sample (packed f16) + GEMM =================
    floatx4 acc[4];
    #pragma unroll
    for (int pt = 0; pt < 4; ++pt) acc[pt] = (floatx4){0.f,0.f,0.f,0.f};

    const _Float16* xcq = xb + m*4;         // this lane's 4-channel base (cq = m)

    for (int tap = 0; tap < 9; ++tap) {
        _Float16* Sb = S + (tap & 1)*4608;
        #pragma unroll
        for (int it = 0; it < 4; ++it) {
            int p  = (w<<4) + it*4 + q;     // position sampled this iter
            int di = p*9 + tap;
            unsigned u0 = dPix[di*2], u1 = dPix[di*2+1];
            float4 wv = *(const float4*)(dW + di*4);
            __half2 w00 = *(__half2*)&wv.x;
            __half2 w01 = *(__half2*)&wv.y;
            __half2 w10 = *(__half2*)&wv.z;
            __half2 w11 = *(__half2*)&wv.w;
            float2 f00 = *(const float2*)(xcq + (u0 & 0xffffu)*64);
            float2 f01 = *(const float2*)(xcq + (u0 >> 16)*64);
            float2 f10 = *(const float2*)(xcq + (u1 & 0xffffu)*64);
            float2 f11 = *(const float2*)(xcq + (u1 >> 16)*64);
            __half2 a0 = *(__half2*)&f00.x, a1 = *(__half2*)&f00.y;
            __half2 b0 = *(__half2*)&f01.x, b1 = *(__half2*)&f01.y;
            __half2 c0 = *(__half2*)&f10.x, c1 = *(__half2*)&f10.y;
            __half2 d0 = *(__half2*)&f11.x, d1 = *(__half2*)&f11.y;
            __half2 s0 = __hfma2(d0, w11, __hfma2(c0, w10, __hfma2(b0, w01, __hmul2(a0, w00))));
            __half2 s1 = __hfma2(d1, w11, __hfma2(c1, w10, __hfma2(b1, w01, __hmul2(a1, w00))));
            float2 sv; sv.x = *(float*)&s0; sv.y = *(float*)&s1;
            *(float2*)(Sb + p*72 + m*4) = sv;    // channels m*4 .. m*4+3
        }
        __syncthreads();
        const half8* wrow = (const half8*)(W2h + (w*16 + m)*576 + tap*64 + q*8);
        half8 bf0 = wrow[0], bf1 = wrow[4];
        #pragma unroll
        for (int pt = 0; pt < 4; ++pt) {
            half8 a0 = *(const half8*)(Sb + (pt*16 + m)*72 + q*8);
            half8 a1 = *(const half8*)(Sb + (pt*16 + m)*72 + 32 + q*8);
            acc[pt] = __builtin_amdgcn_mfma_f32_16x16x32_f16(a0, bf0, acc[pt], 0, 0, 0);
            acc[pt] = __builtin_amdgcn_mfma_f32_16x16x32_f16(a1, bf1, acc[pt], 0, 0, 0);
        }
        // next tap writes the other S buffer; no second barrier needed
    }
    __syncthreads();

    // epilogue B: LDS transpose -> coalesced NCHW stores
    float* E = (float*)smem;   // [64 pos][66]
    #pragma unroll
    for (int pt = 0; pt < 4; ++pt) {
        #pragma unroll
        for (int r = 0; r < 4; ++r)
            E[(pt*16 + q*4 + r)*66 + w*16 + m] = acc[pt][r];
    }
    __syncthreads();
    int obase = (b*64)*HW_ + (i<<7) + j0;
    #pragma unroll
    for (int rep = 0; rep < 16; ++rep) {
        int o = rep*4 + w;
        out[obase + o*HW_ + lane] = E[lane*66 + o] + b_dcn[o];
    }
}

extern "C" void kernel_launch(void* const* d_in, const int* in_sizes, int n_in,
                              void* d_out, int out_size, void* d_ws, size_t ws_size,
                              hipStream_t stream) {
    const float* x     = (const float*)d_in[0];
    const float* w_off = (const float*)d_in[1];
    const float* b_off = (const float*)d_in[2];
    const float* w_dcn = (const float*)d_in[3];
    const float* b_dcn = (const float*)d_in[4];
    float* out = (float*)d_out;

    __half* x_h = (__half*)d_ws;                            // 8,388,608 B
    __half* W2h = (__half*)((char*)d_ws + 8388608);         //    73,728 B
    __half* W0h = (__half*)((char*)d_ws + 8388608 + 73728); //    36,864 B

    k_prep<<<1024 + 216, 256, 0, stream>>>(x, w_dcn, w_off, x_h, W2h, W0h);
    k_fused<<<1024, 256, 0, stream>>>(x_h, (const _Float16*)W2h,
                                      (const _Float16*)W0h, b_off, b_dcn, out);
}

// Round 5
// 116.274 us; speedup vs baseline: 7.0472x; 1.1236x over previous
//
#include <hip/hip_runtime.h>
#include <hip/hip_fp16.h>

#define B_ 4
#define H_ 128
#define W_ 128
#define HW_ 16384

typedef _Float16 half8 __attribute__((ext_vector_type(8)));
typedef float floatx4 __attribute__((ext_vector_type(4)));

// ws layout (bytes):
//   x_h : f16 NHWC [4][128][128][64]                      = 8,388,608
//   W2L : f16 [9 tap][2 ks][4 w][64 lane][8]              =    73,728
//   W0L : f16 [9 tap][2 ks][2 h][64 lane][8]              =    36,864

// ---------------- prep: x NCHW f32 -> NHWC f16 + weight swizzles ----------------
__global__ __launch_bounds__(256) void k_prep(
    const float* __restrict__ x, const float* __restrict__ w_dcn,
    const float* __restrict__ w_off, __half* __restrict__ x_h,
    __half* __restrict__ W2L, __half* __restrict__ W0L)
{
    int bid = blockIdx.x;
    int t = threadIdx.x;
    if (bid < 1024) {
        __shared__ float tile[64][65];
        int base = bid * 64;
        int b = base >> 14;
        int pin = base & (HW_-1);
        #pragma unroll
        for (int it = 0; it < 16; ++it) {
            int c = it*4 + (t >> 6);
            int p = t & 63;
            tile[c][p] = x[b*(64*HW_) + c*HW_ + pin + p];
        }
        __syncthreads();
        #pragma unroll
        for (int it = 0; it < 8; ++it) {
            int p  = it*8 + (t >> 5);
            int c2 = (t & 31) * 2;
            __half2 h2 = __floats2half2_rn(tile[c2][p], tile[c2+1][p]);
            *(__half2*)(x_h + (size_t)(base + p)*64 + c2) = h2;
        }
    } else {
        int idx = (bid - 1024)*256 + t;   // 55296 = 36864 + 18432
        if (idx < 36864) {
            // W2L[(((tap*2+ks)*4+w)*64+lane)*8+e] = w_dcn[o=w*16+(lane&15)][c=ks*32+(lane>>4)*8+e][tap]
            int e = idx & 7, lane = (idx>>3) & 63, w = (idx>>9) & 3;
            int ks = (idx>>11) & 1, tap = idx >> 12;
            int o = w*16 + (lane & 15);
            int c = ks*32 + (lane >> 4)*8 + e;
            W2L[idx] = __float2half(w_dcn[o*576 + c*9 + tap]);
        } else {
            int i2 = idx - 36864;
            // W0L[(((tap*2+ks)*2+h)*64+lane)*8+e]
            int e = i2 & 7, lane = (i2>>3) & 63, h = (i2>>9) & 1;
            int ks = (i2>>10) & 1, tap = i2 >> 11;
            int oc = h*16 + (lane & 15);
            int c = ks*32 + (lane >> 4)*8 + e;
            W0L[i2] = (oc < 18) ? __float2half(w_off[oc*576 + c*9 + tap])
                                : __float2half(0.f);
        }
    }
}

// ---------------- fused kernel ----------------
// block = 256 thr = 4 waves, 64 consecutive positions (half row, i uniform).
// LDS regions (76,800 B total, 2 blocks/CU):
//   halo : [5 row][66 pix][64 ch] f16 = 42,240   (epilogue E[64][66] f32 aliases)
//   S    : [2 buf][64 pos][72 ch] f16 = 18,432   (offL[64][20] f32 aliases start)
//   dPix : [576][2] u32               =  4,608
//   dW   : [576][4] half2             =  9,216
//   dFlag: [576] u32                  =  2,304
#define HALO_OFF  0
#define S_OFF     42240
#define DPIX_OFF  60672
#define DW_OFF    65280
#define DFLAG_OFF 74496

__global__ __launch_bounds__(256, 2) void k_fused(
    const __half* __restrict__ x_hg, const _Float16* __restrict__ W2L,
    const _Float16* __restrict__ W0L, const float* __restrict__ b_off,
    const float* __restrict__ b_dcn, float* __restrict__ out)
{
    __shared__ __attribute__((aligned(16))) char smem[76800];
    char*     halo_c = smem + HALO_OFF;
    _Float16* S      = (_Float16*)(smem + S_OFF);
    float*    offL   = (float*)(smem + S_OFF);        // dead before S's first use
    unsigned* dPix   = (unsigned*)(smem + DPIX_OFF);
    __half2*  dW     = (__half2*)(smem + DW_OFF);
    unsigned* dFlag  = (unsigned*)(smem + DFLAG_OFF);

    int t = threadIdx.x;
    int lane = t & 63;
    int w = __builtin_amdgcn_readfirstlane(t >> 6);
    int m = lane & 15, q = lane >> 4;

    // XCD swizzle: contiguous half-image per XCD
    int bid  = blockIdx.x;
    int orig = (bid & 7)*128 + (bid >> 3);
    int base = orig * 64;
    int b  = base >> 14;
    int p0 = base & (HW_-1);
    int i  = p0 >> 7;
    int j0 = p0 & 127;
    int cb = (j0 == 0) ? 0 : 62;          // halo col base (66 cols staged)

    const _Float16* xb = (const _Float16*)x_hg + (size_t)b * (HW_*64);

    // ---------- stage 5-row x 66-col halo into LDS (dense coalesced) ----------
    // per row: 8448 B = 8 x 1024 B (float4/lane) + 256 B tail (float/lane)
    for (int idx = w; idx < 45; idx += 4) {
        int r = idx / 9, s = idx - r*9;
        int grow = min(max(i - 2 + r, 0), H_-1);
        const char* g = (const char*)(xb + ((grow<<7) + cb)*64);
        char* l = halo_c + r*8448;
        if (s < 8) {
            float4 v = *(const float4*)(g + s*1024 + lane*16);
            *(float4*)(l + s*1024 + lane*16) = v;
        } else {
            float v = *(const float*)(g + 8192 + lane*4);
            *(float*)(l + 8192 + lane*4) = v;
        }
    }
    __syncthreads();

    // ================= Phase A: offset conv from halo =================
    floatx4 accA[2];
    #pragma unroll
    for (int h = 0; h < 2; ++h) accA[h] = (floatx4){0.f,0.f,0.f,0.f};

    const half8 hz = {0,0,0,0,0,0,0,0};
    int pcol = w*16 + m;
    #pragma unroll
    for (int tap = 0; tap < 9; ++tap) {
        int kh = tap/3, kw = tap - (tap/3)*3;
        int ii = i - 1 + kh;
        bool vy = (ii >= 0) && (ii < H_);
        int iic = min(max(ii,0),H_-1);
        int hr = iic - i + 2;                       // in [0,5) always
        int jj = j0 + pcol - 1 + kw;
        bool valid = vy && (jj >= 0) && (jj < W_);
        int jjc = min(max(jj,0),W_-1);
        int hx = jjc - cb;                          // in [0,66) always
        int hb = (hr*66 + hx)*128 + q*16;
        half8 a0 = *(const half8*)(halo_c + hb);
        half8 a1 = *(const half8*)(halo_c + hb + 64);
        a0 = valid ? a0 : hz;
        a1 = valid ? a1 : hz;
        #pragma unroll
        for (int ks = 0; ks < 2; ++ks) {
            half8 a = ks ? a1 : a0;
            #pragma unroll
            for (int h = 0; h < 2; ++h) {
                half8 bf = *(const half8*)(W0L + (((tap*2+ks)*2+h)<<9) + (lane<<3));
                accA[h] = __builtin_amdgcn_mfma_f32_16x16x32_f16(a, bf, accA[h], 0, 0, 0);
            }
        }
    }
    // epilogue A: D layout col=m (=oc), row=q*4+r (=pos in wave tile)
    #pragma unroll
    for (int h = 0; h < 2; ++h) {
        int oc = h*16 + m;
        if (oc < 18) {
            float bo = b_off[oc];
            #pragma unroll
            for (int r = 0; r < 4; ++r) {
                int pos = w*16 + q*4 + r;
                offL[pos*20 + oc] = accA[h][r] + bo;
            }
        }
    }
    __syncthreads();

    // ================= descriptor build: one per (pos, tap) =================
    #pragma unroll
    for (int e = 0; e < 3; ++e) {
        int idx = e*256 + t;
        if (idx < 576) {
            int pos = idx / 9;
            int tap = idx - pos*9;
            int kh = tap/3, kw = tap - (tap/3)*3;
            float2 o2 = *(const float2*)(offL + pos*20 + 2*tap);
            float py = (float)(i - 1 + kh) + o2.x;
            float px = (float)(j0 + pos - 1 + kw) + o2.y;
            float y0f = floorf(py), x0f = floorf(px);
            float dy = py - y0f, dx = px - x0f;
            int y0 = (int)y0f, x0i = (int)x0f;
            int y1 = y0 + 1,  x1 = x0i + 1;
            bool vy0 = (y0>=0)&(y0<H_),   vy1 = (y1>=0)&(y1<H_);
            bool vx0 = (x0i>=0)&(x0i<W_), vx1 = (x1>=0)&(x1<W_);
            int yc0 = min(max(y0,0),H_-1),  yc1 = min(max(y1,0),H_-1);
            int xc0 = min(max(x0i,0),W_-1), xc1 = min(max(x1,0),W_-1);
            float w00 = (1.f-dy)*(1.f-dx) * ((vy0&&vx0)?1.f:0.f);
            float w01 = (1.f-dy)*dx       * ((vy0&&vx1)?1.f:0.f);
            float w10 = dy*(1.f-dx)       * ((vy1&&vx0)?1.f:0.f);
            float w11 = dy*dx             * ((vy1&&vx1)?1.f:0.f);
            // halo coords
            int hy0 = yc0 - i + 2, hy1 = yc1 - i + 2;
            int hx0 = xc0 - cb,    hx1 = xc1 - cb;
            bool inh = (hy0>=0)&(hy0<5)&(hy1>=0)&(hy1<5)
                     & (hx0>=0)&(hx0<66)&(hx1>=0)&(hx1<66);
            unsigned u0, u1;
            if (inh) {   // halo BYTE offsets (max 42,112 < 65,536)
                u0 = (unsigned)((hy0*66+hx0)*128) | ((unsigned)((hy0*66+hx1)*128) << 16);
                u1 = (unsigned)((hy1*66+hx0)*128) | ((unsigned)((hy1*66+hx1)*128) << 16);
            } else {     // global pixel ids
                u0 = (unsigned)((yc0<<7)+xc0) | ((unsigned)((yc0<<7)+xc1) << 16);
                u1 = (unsigned)((yc1<<7)+xc0) | ((unsigned)((yc1<<7)+xc1) << 16);
            }
            dPix[idx*2]   = u0;
            dPix[idx*2+1] = u1;
            dFlag[idx]    = inh ? 0u : 1u;
            __half2 h00 = __floats2half2_rn(w00, w00);
            __half2 h01 = __floats2half2_rn(w01, w01);
            __half2 h10 = __floats2half2_rn(w10, w10);
            __half2 h11 = __floats2half2_rn(w11, w11);
            float4 wv;
            wv.x = *(float*)&h00; wv.y = *(float*)&h01;
            wv.z = *(float*)&h10; wv.w = *(float*)&h11;
            *(float4*)(dW + idx*4) = wv;
        }
    }
    __syncthreads();

    // ================= Phase B: sample from halo + GEMM =================
    floatx4 acc[4];
    #pragma unroll
    for (int pt = 0; pt < 4; ++pt) acc[pt] = (floatx4){0.f,0.f,0.f,0.f};

    const char* halo_m = halo_c + m*8;     // this lane's 4-channel base in halo
    const _Float16* xcq = xb + m*4;        // global fallback base

    for (int tap = 0; tap < 9; ++tap) {
        _Float16* Sb = S + (tap & 1)*4608;
        #pragma unroll
        for (int it = 0; it < 4; ++it) {
            int p  = (w<<4) + it*4 + q;
            int di = p*9 + tap;
            unsigned u0 = dPix[di*2], u1 = dPix[di*2+1];
            unsigned fl = dFlag[di];
            float4 wv = *(const float4*)(dW + di*4);
            __half2 w00 = *(__half2*)&wv.x;
            __half2 w01 = *(__half2*)&wv.y;
            __half2 w10 = *(__half2*)&wv.z;
            __half2 w11 = *(__half2*)&wv.w;
            float2 f00, f01, f10, f11;
            if (fl == 0u) {
                f00 = *(const float2*)(halo_m + (u0 & 0xffffu));
                f01 = *(const float2*)(halo_m + (u0 >> 16));
                f10 = *(const float2*)(halo_m + (u1 & 0xffffu));
                f11 = *(const float2*)(halo_m + (u1 >> 16));
            } else {
                f00 = *(const float2*)(xcq + (u0 & 0xffffu)*64);
                f01 = *(const float2*)(xcq + (u0 >> 16)*64);
                f10 = *(const float2*)(xcq + (u1 & 0xffffu)*64);
                f11 = *(const float2*)(xcq + (u1 >> 16)*64);
            }
            __half2 a0 = *(__half2*)&f00.x, a1 = *(__half2*)&f00.y;
            __half2 b0 = *(__half2*)&f01.x, b1 = *(__half2*)&f01.y;
            __half2 c0 = *(__half2*)&f10.x, c1 = *(__half2*)&f10.y;
            __half2 d0 = *(__half2*)&f11.x, d1 = *(__half2*)&f11.y;
            __half2 s0 = __hfma2(d0, w11, __hfma2(c0, w10, __hfma2(b0, w01, __hmul2(a0, w00))));
            __half2 s1 = __hfma2(d1, w11, __hfma2(c1, w10, __hfma2(b1, w01, __hmul2(a1, w00))));
            float2 sv; sv.x = *(float*)&s0; sv.y = *(float*)&s1;
            *(float2*)(Sb + p*72 + m*4) = sv;
        }
        __syncthreads();
        #pragma unroll
        for (int ks = 0; ks < 2; ++ks) {
            half8 bf = *(const half8*)(W2L + ((((tap*2+ks)<<2)+w)<<9) + (lane<<3));
            #pragma unroll
            for (int pt = 0; pt < 4; ++pt) {
                half8 a = *(const half8*)(Sb + (pt*16 + m)*72 + ks*32 + q*8);
                acc[pt] = __builtin_amdgcn_mfma_f32_16x16x32_f16(a, bf, acc[pt], 0, 0, 0);
            }
        }
        // next tap writes the other S buffer; halo is read-only; no extra barrier
    }

    // epilogue B: E aliases halo (dead: all waves past final barrier are done sampling)
    float* E = (float*)smem;   // [64 pos][66]
    #pragma unroll
    for (int pt = 0; pt < 4; ++pt) {
        #pragma unroll
        for (int r = 0; r < 4; ++r)
            E[(pt*16 + q*4 + r)*66 + w*16 + m] = acc[pt][r];
    }
    __syncthreads();
    int obase = (b*64)*HW_ + (i<<7) + j0;
    #pragma unroll
    for (int rep = 0; rep < 16; ++rep) {
        int o = rep*4 + w;
        out[obase + o*HW_ + lane] = E[lane*66 + o] + b_dcn[o];
    }
}

extern "C" void kernel_launch(void* const* d_in, const int* in_sizes, int n_in,
                              void* d_out, int out_size, void* d_ws, size_t ws_size,
                              hipStream_t stream) {
    const float* x     = (const float*)d_in[0];
    const float* w_off = (const float*)d_in[1];
    const float* b_off = (const float*)d_in[2];
    const float* w_dcn = (const float*)d_in[3];
    const float* b_dcn = (const float*)d_in[4];
    float* out = (float*)d_out;

    __half* x_h = (__half*)d_ws;                            // 8,388,608 B
    __half* W2L = (__half*)((char*)d_ws + 8388608);         //    73,728 B
    __half* W0L = (__half*)((char*)d_ws + 8388608 + 73728); //    36,864 B

    k_prep<<<1024 + 216, 256, 0, stream>>>(x, w_dcn, w_off, x_h, W2L, W0L);
    k_fused<<<1024, 256, 0, stream>>>(x_h, (const _Float16*)W2L,
                                      (const _Float16*)W0L, b_off, b_dcn, out);
}

// Round 6
// 109.171 us; speedup vs baseline: 7.5057x; 1.0651x over previous
//
#include <hip/hip_runtime.h>
#include <hip/hip_fp16.h>

#define B_ 4
#define H_ 128
#define W_ 128
#define HW_ 16384

typedef _Float16 half8 __attribute__((ext_vector_type(8)));
typedef float floatx4 __attribute__((ext_vector_type(4)));

// ws layout (bytes):
//   x_h : f16 NHWC [4][128][128][64]           = 8,388,608
//   W2L : f16 [9 tap][2 ks][4 og][64 lane][8]  =    73,728
//   W0L : f16 [9 tap][2 ks][2 h][64 lane][8]   =    36,864

// ---------------- prep: x NCHW f32 -> NHWC f16 + weight swizzles ----------------
__global__ __launch_bounds__(256) void k_prep(
    const float* __restrict__ x, const float* __restrict__ w_dcn,
    const float* __restrict__ w_off, __half* __restrict__ x_h,
    __half* __restrict__ W2L, __half* __restrict__ W0L)
{
    int bid = blockIdx.x;
    int t = threadIdx.x;
    if (bid < 1024) {
        __shared__ float tile[64][65];
        int base = bid * 64;
        int b = base >> 14;
        int pin = base & (HW_-1);
        #pragma unroll
        for (int it = 0; it < 16; ++it) {
            int c = it*4 + (t >> 6);
            int p = t & 63;
            tile[c][p] = x[b*(64*HW_) + c*HW_ + pin + p];
        }
        __syncthreads();
        #pragma unroll
        for (int it = 0; it < 8; ++it) {
            int p  = it*8 + (t >> 5);
            int c2 = (t & 31) * 2;
            __half2 h2 = __floats2half2_rn(tile[c2][p], tile[c2+1][p]);
            *(__half2*)(x_h + (size_t)(base + p)*64 + c2) = h2;
        }
    } else {
        int idx = (bid - 1024)*256 + t;   // 55296 = 36864 + 18432
        if (idx < 36864) {
            // W2L[(((tap*2+ks)*4+og)*64+lane)*8+e] = w_dcn[o=og*16+(lane&15)][c=ks*32+(lane>>4)*8+e][tap]
            int e = idx & 7, lane = (idx>>3) & 63, og = (idx>>9) & 3;
            int ks = (idx>>11) & 1, tap = idx >> 12;
            int o = og*16 + (lane & 15);
            int c = ks*32 + (lane >> 4)*8 + e;
            W2L[idx] = __float2half(w_dcn[o*576 + c*9 + tap]);
        } else {
            int i2 = idx - 36864;
            // W0L[(((tap*2+ks)*2+h)*64+lane)*8+e]
            int e = i2 & 7, lane = (i2>>3) & 63, h = (i2>>9) & 1;
            int ks = (i2>>10) & 1, tap = i2 >> 11;
            int oc = h*16 + (lane & 15);
            int c = ks*32 + (lane >> 4)*8 + e;
            W0L[i2] = (oc < 18) ? __float2half(w_off[oc*576 + c*9 + tap])
                                : __float2half(0.f);
        }
    }
}

// ---------------- fused kernel ----------------
// block = 256 thr = 4 waves, 64 consecutive positions (half row, i uniform).
// lane (m,q) of wave w OWNS pos = w*16+m, channel chunks q (ks=0) and q+4 (ks=1)
// == exactly its MFMA A-fragment. No S tile, no per-tap barriers.
// LDS (51,456 B -> 3 blocks/CU):
//   haloT: [8 chunk][330 pix][16 B] = 42,240   (chunk stride 5280 B -> bank-balanced)
//   desc : [576][16 B]              =  9,216   (aliases offL[64][20] f32, built via regs)
//   epilogue E[64][66] f32 = 16,896 aliases haloT after final barrier
#define CHS 5280
#define DESC_OFF 42240

__global__ __launch_bounds__(256, 3) void k_fused(
    const __half* __restrict__ x_hg, const _Float16* __restrict__ W2L,
    const _Float16* __restrict__ W0L, const float* __restrict__ b_off,
    const float* __restrict__ b_dcn, float* __restrict__ out)
{
    __shared__ __attribute__((aligned(16))) char smem[51456];
    char*     halo_c = smem;
    float*    offL   = (float*)(smem + DESC_OFF);
    char*     desc   = smem + DESC_OFF;

    int t = threadIdx.x;
    int lane = t & 63;
    int w = __builtin_amdgcn_readfirstlane(t >> 6);
    int m = lane & 15, q = lane >> 4;

    // XCD swizzle: contiguous half-image per XCD
    int bid  = blockIdx.x;
    int orig = (bid & 7)*128 + (bid >> 3);
    int base = orig * 64;
    int b  = base >> 14;
    int p0 = base & (HW_-1);
    int i  = p0 >> 7;
    int j0 = p0 & 127;
    int cb = (j0 == 0) ? 0 : 62;          // halo col base (66 cols staged)

    const _Float16* xb = (const _Float16*)x_hg + (size_t)b * (HW_*64);

    // ---------- stage 5-row x 66-col halo, chunk-transposed ----------
    {
        int pl8 = lane >> 3, ch = lane & 7;
        for (int idx = w; idx < 42; idx += 4) {
            int pl = idx*8 + pl8;                 // pixel id 0..335
            if (pl < 330) {
                int r = pl / 66, hx = pl - r*66;
                int grow = min(max(i - 2 + r, 0), H_-1);
                int gcol = cb + hx;
                half8 v = *(const half8*)(xb + ((grow<<7) + gcol)*64 + ch*8);
                *(half8*)(halo_c + ch*CHS + pl*16) = v;
            }
        }
    }
    __syncthreads();

    // ================= Phase A: offset conv from haloT =================
    floatx4 accA[2];
    #pragma unroll
    for (int h = 0; h < 2; ++h) accA[h] = (floatx4){0.f,0.f,0.f,0.f};

    const half8 hz = {0,0,0,0,0,0,0,0};
    int pcol = w*16 + m;
    #pragma unroll
    for (int tap = 0; tap < 9; ++tap) {
        int kh = tap/3, kw = tap - (tap/3)*3;
        int ii = i - 1 + kh;
        bool vy = (ii >= 0) && (ii < H_);
        int iic = min(max(ii,0),H_-1);
        int jj = j0 + pcol - 1 + kw;
        bool valid = vy && (jj >= 0) && (jj < W_);
        int jjc = min(max(jj,0),W_-1);
        int pixA = (iic - i + 2)*66 + (jjc - cb);   // in [0,330)
        half8 a0 = *(const half8*)(halo_c + q*CHS     + pixA*16);
        half8 a1 = *(const half8*)(halo_c + (q+4)*CHS + pixA*16);
        a0 = valid ? a0 : hz;
        a1 = valid ? a1 : hz;
        #pragma unroll
        for (int ks = 0; ks < 2; ++ks) {
            half8 a = ks ? a1 : a0;
            #pragma unroll
            for (int h = 0; h < 2; ++h) {
                half8 bf = *(const half8*)(W0L + (((tap*2+ks)*2+h)<<9) + (lane<<3));
                accA[h] = __builtin_amdgcn_mfma_f32_16x16x32_f16(a, bf, accA[h], 0, 0, 0);
            }
        }
    }
    // epilogue A: D col=m (=oc), row=q*4+r (=pos in wave tile)
    #pragma unroll
    for (int h = 0; h < 2; ++h) {
        int oc = h*16 + m;
        if (oc < 18) {
            float bo = b_off[oc];
            #pragma unroll
            for (int r = 0; r < 4; ++r)
                offL[(w*16 + q*4 + r)*20 + oc] = accA[h][r] + bo;
        }
    }
    __syncthreads();

    // ======== descriptor build: regs first (desc aliases offL), then store ========
    uint4 dreg[3];
    #pragma unroll
    for (int e = 0; e < 3; ++e) {
        int idx = e*256 + t;
        if (idx < 576) {
            int pos = idx / 9;
            int tap = idx - pos*9;
            int kh = tap/3, kw = tap - (tap/3)*3;
            float2 o2 = *(const float2*)(offL + pos*20 + 2*tap);
            float py = (float)(i - 1 + kh) + o2.x;
            float px = (float)(j0 + pos - 1 + kw) + o2.y;
            float y0f = floorf(py), x0f = floorf(px);
            float dy = py - y0f, dx = px - x0f;
            int y0 = (int)y0f, x0i = (int)x0f;
            int y1 = y0 + 1,  x1 = x0i + 1;
            bool vy0 = (y0>=0)&(y0<H_),   vy1 = (y1>=0)&(y1<H_);
            bool vx0 = (x0i>=0)&(x0i<W_), vx1 = (x1>=0)&(x1<W_);
            int yc0 = min(max(y0,0),H_-1),  yc1 = min(max(y1,0),H_-1);
            int xc0 = min(max(x0i,0),W_-1), xc1 = min(max(x1,0),W_-1);
            float w00 = (1.f-dy)*(1.f-dx) * ((vy0&&vx0)?1.f:0.f);
            float w01 = (1.f-dy)*dx       * ((vy0&&vx1)?1.f:0.f);
            float w10 = dy*(1.f-dx)       * ((vy1&&vx0)?1.f:0.f);
            float w11 = dy*dx             * ((vy1&&vx1)?1.f:0.f);
            int hy0 = yc0 - i + 2, hy1 = yc1 - i + 2;
            int hx0 = xc0 - cb,    hx1 = xc1 - cb;
            bool inh = (hy0>=0)&(hy0<5)&(hy1>=0)&(hy1<5)
                     & (hx0>=0)&(hx0<66)&(hx1>=0)&(hx1<66);
            unsigned a0,a1,a2,a3;
            if (inh) { a0 = hy0*66+hx0; a1 = hy0*66+hx1; a2 = hy1*66+hx0; a3 = hy1*66+hx1; }
            else     { a0 = ((yc0<<7)+xc0) | 0x8000u; a1 = (yc0<<7)+xc1;
                       a2 = (yc1<<7)+xc0;             a3 = (yc1<<7)+xc1; }
            __half2 hw0 = __floats2half2_rn(w00, w01);
            __half2 hw1 = __floats2half2_rn(w10, w11);
            dreg[e].x = a0 | (a1 << 16);
            dreg[e].y = a2 | (a3 << 16);
            dreg[e].z = *(unsigned*)&hw0;
            dreg[e].w = *(unsigned*)&hw1;
        }
    }
    __syncthreads();
    #pragma unroll
    for (int e = 0; e < 3; ++e) {
        int idx = e*256 + t;
        if (idx < 576) *(uint4*)(desc + idx*16) = dreg[e];
    }
    __syncthreads();

    // ================= Phase B: own-pos sample + MFMA, barrier-free =================
    floatx4 acc[4];
    #pragma unroll
    for (int og = 0; og < 4; ++og) acc[og] = (floatx4){0.f,0.f,0.f,0.f};

    const char* hq0 = halo_c + q*CHS;
    const char* hq1 = halo_c + (q+4)*CHS;
    const _Float16* xq0 = xb + q*8;          // global fallback chunk bases
    const _Float16* xq1 = xb + 32 + q*8;
    int mypos = w*16 + m;

    for (int tap = 0; tap < 9; ++tap) {
        uint4 d = *(const uint4*)(desc + (mypos*9 + tap)*16);
        unsigned p0i = d.x & 0x7fffu, p1i = d.x >> 16;
        unsigned p2i = d.y & 0xffffu, p3i = d.y >> 16;
        bool inh = (d.x & 0x8000u) == 0u;
        unsigned short b00 = (unsigned short)(d.z & 0xffffu);
        unsigned short b01 = (unsigned short)(d.z >> 16);
        unsigned short b10 = (unsigned short)(d.w & 0xffffu);
        unsigned short b11 = (unsigned short)(d.w >> 16);
        _Float16 h00 = *(_Float16*)&b00, h01 = *(_Float16*)&b01;
        _Float16 h10 = *(_Float16*)&b10, h11 = *(_Float16*)&b11;
        half8 W00 = {h00,h00,h00,h00,h00,h00,h00,h00};
        half8 W01 = {h01,h01,h01,h01,h01,h01,h01,h01};
        half8 W10 = {h10,h10,h10,h10,h10,h10,h10,h10};
        half8 W11 = {h11,h11,h11,h11,h11,h11,h11,h11};
        half8 v00a,v01a,v10a,v11a, v00b,v01b,v10b,v11b;
        if (inh) {
            v00a = *(const half8*)(hq0 + p0i*16);  v00b = *(const half8*)(hq1 + p0i*16);
            v01a = *(const half8*)(hq0 + p1i*16);  v01b = *(const half8*)(hq1 + p1i*16);
            v10a = *(const half8*)(hq0 + p2i*16);  v10b = *(const half8*)(hq1 + p2i*16);
            v11a = *(const half8*)(hq0 + p3i*16);  v11b = *(const half8*)(hq1 + p3i*16);
        } else {
            v00a = *(const half8*)(xq0 + p0i*64);  v00b = *(const half8*)(xq1 + p0i*64);
            v01a = *(const half8*)(xq0 + p1i*64);  v01b = *(const half8*)(xq1 + p1i*64);
            v10a = *(const half8*)(xq0 + p2i*64);  v10b = *(const half8*)(xq1 + p2i*64);
            v11a = *(const half8*)(xq0 + p3i*64);  v11b = *(const half8*)(xq1 + p3i*64);
        }
        half8 sk0 = v00a*W00 + v01a*W01 + v10a*W10 + v11a*W11;
        half8 sk1 = v00b*W00 + v01b*W01 + v10b*W10 + v11b*W11;
        #pragma unroll
        for (int og = 0; og < 4; ++og) {
            half8 bf0 = *(const half8*)(W2L + (((tap*2+0)*4+og)<<9) + (lane<<3));
            acc[og] = __builtin_amdgcn_mfma_f32_16x16x32_f16(sk0, bf0, acc[og], 0, 0, 0);
            half8 bf1 = *(const half8*)(W2L + (((tap*2+1)*4+og)<<9) + (lane<<3));
            acc[og] = __builtin_amdgcn_mfma_f32_16x16x32_f16(sk1, bf1, acc[og], 0, 0, 0);
        }
    }
    __syncthreads();   // halo dead; epilogue E aliases it

    // epilogue: D col=m -> o=og*16+m, row=q*4+r -> pos=w*16+q*4+r
    float* E = (float*)smem;   // [64 pos][66]
    #pragma unroll
    for (int og = 0; og < 4; ++og) {
        #pragma unroll
        for (int r = 0; r < 4; ++r)
            E[(w*16 + q*4 + r)*66 + og*16 + m] = acc[og][r];
    }
    __syncthreads();
    int obase = (b*64)*HW_ + (i<<7) + j0;
    #pragma unroll
    for (int rep = 0; rep < 16; ++rep) {
        int o = rep*4 + w;
        out[obase + o*HW_ + lane] = E[lane*66 + o] + b_dcn[o];
    }
}

extern "C" void kernel_launch(void* const* d_in, const int* in_sizes, int n_in,
                              void* d_out, int out_size, void* d_ws, size_t ws_size,
                              hipStream_t stream) {
    const float* x     = (const float*)d_in[0];
    const float* w_off = (const float*)d_in[1];
    const float* b_off = (const float*)d_in[2];
    const float* w_dcn = (const float*)d_in[3];
    const float* b_dcn = (const float*)d_in[4];
    float* out = (float*)d_out;

    __half* x_h = (__half*)d_ws;                            // 8,388,608 B
    __half* W2L = (__half*)((char*)d_ws + 8388608);         //    73,728 B
    __half* W0L = (__half*)((char*)d_ws + 8388608 + 73728); //    36,864 B

    k_prep<<<1024 + 216, 256, 0, stream>>>(x, w_dcn, w_off, x_h, W2L, W0L);
    k_fused<<<1024, 256, 0, stream>>>(x_h, (const _Float16*)W2L,
                                      (const _Float16*)W0L, b_off, b_dcn, out);
}

// Round 7
// 105.168 us; speedup vs baseline: 7.7914x; 1.0381x over previous
//
#include <hip/hip_runtime.h>
#include <hip/hip_fp16.h>

#define B_ 4
#define H_ 128
#define W_ 128
#define HW_ 16384

typedef _Float16 half8 __attribute__((ext_vector_type(8)));
typedef float floatx4 __attribute__((ext_vector_type(4)));

// ws layout (bytes):
//   x_h : f16 NHWC [4][128][128][64]           = 8,388,608
//   W2L : f16 [9 tap][2 ks][4 og][64 lane][8]  =    73,728
//   W0L : f16 [9 tap][2 ks][2 h][64 lane][8]   =    36,864

// ---------------- prep: x NCHW f32 -> NHWC f16 + weight swizzles ----------------
__global__ __launch_bounds__(256) void k_prep(
    const float* __restrict__ x, const float* __restrict__ w_dcn,
    const float* __restrict__ w_off, __half* __restrict__ x_h,
    __half* __restrict__ W2L, __half* __restrict__ W0L)
{
    int bid = blockIdx.x;
    int t = threadIdx.x;
    if (bid < 1024) {
        __shared__ float tile[64][65];
        int base = bid * 64;
        int b = base >> 14;
        int pin = base & (HW_-1);
        #pragma unroll
        for (int it = 0; it < 16; ++it) {
            int c = it*4 + (t >> 6);
            int p = t & 63;
            tile[c][p] = x[b*(64*HW_) + c*HW_ + pin + p];
        }
        __syncthreads();
        #pragma unroll
        for (int it = 0; it < 8; ++it) {
            int p  = it*8 + (t >> 5);
            int c2 = (t & 31) * 2;
            __half2 h2 = __floats2half2_rn(tile[c2][p], tile[c2+1][p]);
            *(__half2*)(x_h + (size_t)(base + p)*64 + c2) = h2;
        }
    } else {
        int idx = (bid - 1024)*256 + t;   // 55296 = 36864 + 18432
        if (idx < 36864) {
            int e = idx & 7, lane = (idx>>3) & 63, og = (idx>>9) & 3;
            int ks = (idx>>11) & 1, tap = idx >> 12;
            int o = og*16 + (lane & 15);
            int c = ks*32 + (lane >> 4)*8 + e;
            W2L[idx] = __float2half(w_dcn[o*576 + c*9 + tap]);
        } else {
            int i2 = idx - 36864;
            int e = i2 & 7, lane = (i2>>3) & 63, h = (i2>>9) & 1;
            int ks = (i2>>10) & 1, tap = i2 >> 11;
            int oc = h*16 + (lane & 15);
            int c = ks*32 + (lane >> 4)*8 + e;
            W0L[i2] = (oc < 18) ? __float2half(w_off[oc*576 + c*9 + tap])
                                : __float2half(0.f);
        }
    }
}

// ---------------- fused kernel ----------------
// block = 256 thr = 4 waves, 64 positions as a 2-row x 32-col tile.
// lane (m,q) of wave w OWNS pos = w*16+m (r=pos>>5,c=pos&31), channel chunks q / q+4
// == exactly its MFMA A-fragment. Barrier-free tap loops.
// LDS (37,120 B -> 4 blocks/CU with VGPR<=128):
//   haloT: [8 chunk][216 pix(6r x 36c)] b128, chunk stride 3488 B (872w = 8 mod 32
//          -> 8-words/bank-optimal for both staged writes and fragment reads)
//   desc : [576][16 B] (aliases offL[64][20] f32; built via regs)
//   epilogue E[64][66] f32 = 16,896 aliases haloT after final barrier
#define CHS2 3488
#define DESC_OFF 27904
#define SMEM_SZ 37120

__global__ __launch_bounds__(256, 4) void k_fused(
    const __half* __restrict__ x_hg, const _Float16* __restrict__ W2L,
    const _Float16* __restrict__ W0L, const float* __restrict__ b_off,
    const float* __restrict__ b_dcn, float* __restrict__ out)
{
    __shared__ __attribute__((aligned(16))) char smem[SMEM_SZ];
    char*     halo_c = smem;
    float*    offL   = (float*)(smem + DESC_OFF);
    char*     desc   = smem + DESC_OFF;

    int t = threadIdx.x;
    int lane = t & 63;
    int w = __builtin_amdgcn_readfirstlane(t >> 6);
    int m = lane & 15, q = lane >> 4;

    // XCD swizzle: contiguous half-image (one batch half) per XCD
    int bid  = blockIdx.x;
    int xcd  = bid & 7, sidx = bid >> 3;
    int orig = xcd*128 + sidx;
    int b    = orig >> 8;
    int rem  = orig & 255;
    int i0   = (rem >> 2) * 2;     // row-pair base
    int j0   = (rem & 3) * 32;     // col base

    const _Float16* xb = (const _Float16*)x_hg + (size_t)b * (HW_*64);

    // ---------- stage 6-row x 36-col halo, chunk-transposed ----------
    for (int idx = t; idx < 1728; idx += 256) {
        int ch = idx & 7, pl = idx >> 3;        // pl = hr*36+hx, 0..215
        int hr = pl / 36, hx = pl - hr*36;
        int grow = min(max(i0 - 2 + hr, 0), H_-1);
        int gcol = min(max(j0 - 2 + hx, 0), W_-1);
        half8 v = *(const half8*)(xb + ((grow<<7) + gcol)*64 + ch*8);
        *(half8*)(halo_c + ch*CHS2 + pl*16) = v;
    }
    __syncthreads();

    // ================= Phase A: offset conv from haloT =================
    floatx4 accA[2];
    #pragma unroll
    for (int h = 0; h < 2; ++h) accA[h] = (floatx4){0.f,0.f,0.f,0.f};

    const half8 hz = {0,0,0,0,0,0,0,0};
    int pcol = w*16 + m;
    int rA = pcol >> 5, cA = pcol & 31;
    #pragma unroll
    for (int tap = 0; tap < 9; ++tap) {
        int kh = tap/3, kw = tap - (tap/3)*3;
        int ii = i0 + rA - 1 + kh;
        int jj = j0 + cA - 1 + kw;
        bool valid = (ii >= 0) && (ii < H_) && (jj >= 0) && (jj < W_);
        int pixA = (rA + 1 + kh)*36 + (cA + 1 + kw);    // in [37,178] always
        half8 a0 = *(const half8*)(halo_c + q*CHS2     + pixA*16);
        half8 a1 = *(const half8*)(halo_c + (q+4)*CHS2 + pixA*16);
        a0 = valid ? a0 : hz;
        a1 = valid ? a1 : hz;
        #pragma unroll
        for (int ks = 0; ks < 2; ++ks) {
            half8 a = ks ? a1 : a0;
            #pragma unroll
            for (int h = 0; h < 2; ++h) {
                half8 bf = *(const half8*)(W0L + (((tap*2+ks)*2+h)<<9) + (lane<<3));
                accA[h] = __builtin_amdgcn_mfma_f32_16x16x32_f16(a, bf, accA[h], 0, 0, 0);
            }
        }
    }
    // epilogue A: D col=m (=oc), row=q*4+r (=pos in wave tile)
    #pragma unroll
    for (int h = 0; h < 2; ++h) {
        int oc = h*16 + m;
        if (oc < 18) {
            float bo = b_off[oc];
            #pragma unroll
            for (int r = 0; r < 4; ++r)
                offL[(w*16 + q*4 + r)*20 + oc] = accA[h][r] + bo;
        }
    }
    __syncthreads();

    // ======== descriptor build: regs first (desc aliases offL), then store ========
    uint4 dreg[3];
    #pragma unroll
    for (int e = 0; e < 3; ++e) {
        int idx = e*256 + t;
        if (idx < 576) {
            int pos = idx / 9;
            int tap = idx - pos*9;
            int kh = tap/3, kw = tap - (tap/3)*3;
            int r = pos >> 5, c = pos & 31;
            float2 o2 = *(const float2*)(offL + pos*20 + 2*tap);
            float py = (float)(i0 + r - 1 + kh) + o2.x;
            float px = (float)(j0 + c - 1 + kw) + o2.y;
            float y0f = floorf(py), x0f = floorf(px);
            float dy = py - y0f, dx = px - x0f;
            int y0 = (int)y0f, x0i = (int)x0f;
            int y1 = y0 + 1,  x1 = x0i + 1;
            bool vy0 = (y0>=0)&(y0<H_),   vy1 = (y1>=0)&(y1<H_);
            bool vx0 = (x0i>=0)&(x0i<W_), vx1 = (x1>=0)&(x1<W_);
            int yc0 = min(max(y0,0),H_-1),  yc1 = min(max(y1,0),H_-1);
            int xc0 = min(max(x0i,0),W_-1), xc1 = min(max(x1,0),W_-1);
            float w00 = (1.f-dy)*(1.f-dx) * ((vy0&&vx0)?1.f:0.f);
            float w01 = (1.f-dy)*dx       * ((vy0&&vx1)?1.f:0.f);
            float w10 = dy*(1.f-dx)       * ((vy1&&vx0)?1.f:0.f);
            float w11 = dy*dx             * ((vy1&&vx1)?1.f:0.f);
            int hy0 = yc0 - (i0-2), hy1 = yc1 - (i0-2);
            int hx0 = xc0 - (j0-2), hx1 = xc1 - (j0-2);
            bool inh = (hy0>=0)&(hy0<6)&(hy1>=0)&(hy1<6)
                     & (hx0>=0)&(hx0<36)&(hx1>=0)&(hx1<36);
            unsigned a0,a1,a2,a3;
            if (inh) { a0 = hy0*36+hx0; a1 = hy0*36+hx1; a2 = hy1*36+hx0; a3 = hy1*36+hx1; }
            else     { a0 = ((yc0<<7)+xc0) | 0x8000u; a1 = (yc0<<7)+xc1;
                       a2 = (yc1<<7)+xc0;             a3 = (yc1<<7)+xc1; }
            __half2 hw0 = __floats2half2_rn(w00, w01);
            __half2 hw1 = __floats2half2_rn(w10, w11);
            dreg[e].x = a0 | (a1 << 16);
            dreg[e].y = a2 | (a3 << 16);
            dreg[e].z = *(unsigned*)&hw0;
            dreg[e].w = *(unsigned*)&hw1;
        }
    }
    __syncthreads();
    #pragma unroll
    for (int e = 0; e < 3; ++e) {
        int idx = e*256 + t;
        if (idx < 576) *(uint4*)(desc + idx*16) = dreg[e];
    }
    __syncthreads();

    // ================= Phase B: own-pos sample + MFMA, barrier-free =================
    floatx4 acc[4];
    #pragma unroll
    for (int og = 0; og < 4; ++og) acc[og] = (floatx4){0.f,0.f,0.f,0.f};

    const char* hq0 = halo_c + q*CHS2;
    const char* hq1 = halo_c + (q+4)*CHS2;
    const _Float16* xq0 = xb + q*8;          // global fallback chunk bases
    const _Float16* xq1 = xb + 32 + q*8;
    int mypos = w*16 + m;

    #pragma unroll 3
    for (int tap = 0; tap < 9; ++tap) {
        uint4 d = *(const uint4*)(desc + (mypos*9 + tap)*16);
        unsigned p0i = d.x & 0x7fffu, p1i = d.x >> 16;
        unsigned p2i = d.y & 0xffffu, p3i = d.y >> 16;
        bool inh = (d.x & 0x8000u) == 0u;
        unsigned short b00 = (unsigned short)(d.z & 0xffffu);
        unsigned short b01 = (unsigned short)(d.z >> 16);
        unsigned short b10 = (unsigned short)(d.w & 0xffffu);
        unsigned short b11 = (unsigned short)(d.w >> 16);
        _Float16 h00 = *(_Float16*)&b00, h01 = *(_Float16*)&b01;
        _Float16 h10 = *(_Float16*)&b10, h11 = *(_Float16*)&b11;
        half8 W00 = {h00,h00,h00,h00,h00,h00,h00,h00};
        half8 W01 = {h01,h01,h01,h01,h01,h01,h01,h01};
        half8 W10 = {h10,h10,h10,h10,h10,h10,h10,h10};
        half8 W11 = {h11,h11,h11,h11,h11,h11,h11,h11};
        half8 v00a,v01a,v10a,v11a, v00b,v01b,v10b,v11b;
        if (inh) {
            v00a = *(const half8*)(hq0 + p0i*16);  v00b = *(const half8*)(hq1 + p0i*16);
            v01a = *(const half8*)(hq0 + p1i*16);  v01b = *(const half8*)(hq1 + p1i*16);
            v10a = *(const half8*)(hq0 + p2i*16);  v10b = *(const half8*)(hq1 + p2i*16);
            v11a = *(const half8*)(hq0 + p3i*16);  v11b = *(const half8*)(hq1 + p3i*16);
        } else {
            v00a = *(const half8*)(xq0 + p0i*64);  v00b = *(const half8*)(xq1 + p0i*64);
            v01a = *(const half8*)(xq0 + p1i*64);  v01b = *(const half8*)(xq1 + p1i*64);
            v10a = *(const half8*)(xq0 + p2i*64);  v10b = *(const half8*)(xq1 + p2i*64);
            v11a = *(const half8*)(xq0 + p3i*64);  v11b = *(const half8*)(xq1 + p3i*64);
        }
        half8 sk0 = v00a*W00 + v01a*W01 + v10a*W10 + v11a*W11;
        half8 sk1 = v00b*W00 + v01b*W01 + v10b*W10 + v11b*W11;
        #pragma unroll
        for (int og = 0; og < 4; ++og) {
            half8 bf0 = *(const half8*)(W2L + (((tap*2+0)*4+og)<<9) + (lane<<3));
            acc[og] = __builtin_amdgcn_mfma_f32_16x16x32_f16(sk0, bf0, acc[og], 0, 0, 0);
            half8 bf1 = *(const half8*)(W2L + (((tap*2+1)*4+og)<<9) + (lane<<3));
            acc[og] = __builtin_amdgcn_mfma_f32_16x16x32_f16(sk1, bf1, acc[og], 0, 0, 0);
        }
    }
    __syncthreads();   // halo dead; epilogue E aliases it

    // epilogue: D col=m -> o=og*16+m, row=q*4+r -> pos=w*16+q*4+r
    float* E = (float*)smem;   // [64 pos][66]
    #pragma unroll
    for (int og = 0; og < 4; ++og) {
        #pragma unroll
        for (int r = 0; r < 4; ++r)
            E[(w*16 + q*4 + r)*66 + og*16 + m] = acc[og][r];
    }
    __syncthreads();
    int obase = (b*64)*HW_ + i0*W_ + j0;
    int orow = (lane >> 5)*W_ + (lane & 31);
    #pragma unroll
    for (int rep = 0; rep < 16; ++rep) {
        int o = rep*4 + w;
        out[obase + o*HW_ + orow] = E[lane*66 + o] + b_dcn[o];
    }
}

extern "C" void kernel_launch(void* const* d_in, const int* in_sizes, int n_in,
                              void* d_out, int out_size, void* d_ws, size_t ws_size,
                              hipStream_t stream) {
    const float* x     = (const float*)d_in[0];
    const float* w_off = (const float*)d_in[1];
    const float* b_off = (const float*)d_in[2];
    const float* w_dcn = (const float*)d_in[3];
    const float* b_dcn = (const float*)d_in[4];
    float* out = (float*)d_out;

    __half* x_h = (__half*)d_ws;                            // 8,388,608 B
    __half* W2L = (__half*)((char*)d_ws + 8388608);         //    73,728 B
    __half* W0L = (__half*)((char*)d_ws + 8388608 + 73728); //    36,864 B

    k_prep<<<1024 + 216, 256, 0, stream>>>(x, w_dcn, w_off, x_h, W2L, W0L);
    k_fused<<<1024, 256, 0, stream>>>(x_h, (const _Float16*)W2L,
                                      (const _Float16*)W0L, b_off, b_dcn, out);
}

// Round 8
// 96.945 us; speedup vs baseline: 8.4523x; 1.0848x over previous
//
#include <hip/hip_runtime.h>
#include <hip/hip_fp16.h>

#define B_ 4
#define H_ 128
#define W_ 128
#define HW_ 16384

typedef _Float16 half8 __attribute__((ext_vector_type(8)));
typedef float floatx4 __attribute__((ext_vector_type(4)));

// ws layout (bytes):
//   W2L : f16 [9 tap][2 ks][4 og][64 lane][8]  = 73,728   at offset 0
//   W0L : f16 [9 tap][2 ks][2 h][64 lane][8]   = 36,864   at offset 73,728

// ---------------- prep: weight swizzles only (216 blocks x 256 = 55,296 elems) ----
__global__ __launch_bounds__(256) void k_prep_w(
    const float* __restrict__ w_dcn, const float* __restrict__ w_off,
    __half* __restrict__ W2L, __half* __restrict__ W0L)
{
    int idx = blockIdx.x*256 + threadIdx.x;     // exactly 55,296 threads
    if (idx < 36864) {
        int e = idx & 7, lane = (idx>>3) & 63, og = (idx>>9) & 3;
        int ks = (idx>>11) & 1, tap = idx >> 12;
        int o = og*16 + (lane & 15);
        int c = ks*32 + (lane >> 4)*8 + e;
        W2L[idx] = __float2half(w_dcn[o*576 + c*9 + tap]);
    } else {
        int i2 = idx - 36864;
        int e = i2 & 7, lane = (i2>>3) & 63, h = (i2>>9) & 1;
        int ks = (i2>>10) & 1, tap = i2 >> 11;
        int oc = h*16 + (lane & 15);
        int c = ks*32 + (lane >> 4)*8 + e;
        W0L[i2] = (oc < 18) ? __float2half(w_off[oc*576 + c*9 + tap])
                            : __float2half(0.f);
    }
}

// ---------------- fused kernel ----------------
// block = 256 thr = 4 waves, 64 positions as a 2-row x 32-col tile.
// Stages its halo DIRECTLY from f32 NCHW x (convert in-flight) — no x_h pass.
// lane (m,q) of wave w OWNS pos = w*16+m, channel chunks q / q+4 == its MFMA A-frag.
// LDS (37,120 B -> 4 blocks/CU with VGPR<=128):
//   haloT: [8 chunk][216 pix(6r x 36c)] b128, chunk stride 3488 B
//   desc : [576][16 B] (aliases offL[64][20] f32; built via regs)
//   epilogue E[64][66] f32 aliases haloT after final barrier
#define CHS2 3488
#define DESC_OFF 27904
#define SMEM_SZ 37120

__global__ __launch_bounds__(256, 4) void k_fused(
    const float* __restrict__ x, const _Float16* __restrict__ W2L,
    const _Float16* __restrict__ W0L, const float* __restrict__ b_off,
    const float* __restrict__ b_dcn, float* __restrict__ out)
{
    __shared__ __attribute__((aligned(16))) char smem[SMEM_SZ];
    char*     halo_c = smem;
    float*    offL   = (float*)(smem + DESC_OFF);
    char*     desc   = smem + DESC_OFF;

    int t = threadIdx.x;
    int lane = t & 63;
    int w = __builtin_amdgcn_readfirstlane(t >> 6);
    int m = lane & 15, q = lane >> 4;

    // XCD swizzle: contiguous half-image (one batch half) per XCD
    int bid  = blockIdx.x;
    int xcd  = bid & 7, sidx = bid >> 3;
    int orig = xcd*128 + sidx;
    int b    = orig >> 8;
    int rem  = orig & 255;
    int i0   = (rem >> 2) * 2;     // row-pair base
    int j0   = (rem & 3) * 32;     // col base

    const float* xf = x + (size_t)b * (64*HW_);

    // ---------- stage 6-row x 36-col halo from f32 NCHW, chunk-transposed ----------
    // task = (chunk ch, pixel pl): 8 coalesced dword loads (slabs ch*8..ch*8+7),
    // convert, one linear ds_write_b128 (1 KB/wave-instr -> bank-wrap optimal).
    #pragma unroll
    for (int rep = 0; rep < 7; ++rep) {
        int idx = rep*256 + t;                  // 1728 tasks
        if (idx < 1728) {
            int ch = idx / 216, pl = idx - ch*216;
            int hr = pl / 36, hx = pl - hr*36;
            int grow = min(max(i0 - 2 + hr, 0), H_-1);
            int gcol = min(max(j0 - 2 + hx, 0), W_-1);
            int gpix = (grow<<7) + gcol;
            const float* s = xf + ch*8*HW_ + gpix;
            half8 v;
            #pragma unroll
            for (int e = 0; e < 8; ++e) v[e] = (_Float16)s[e*HW_];
            *(half8*)(halo_c + ch*CHS2 + pl*16) = v;
        }
    }
    __syncthreads();

    // ================= Phase A: offset conv from haloT =================
    floatx4 accA[2];
    #pragma unroll
    for (int h = 0; h < 2; ++h) accA[h] = (floatx4){0.f,0.f,0.f,0.f};

    const half8 hz = {0,0,0,0,0,0,0,0};
    int pcol = w*16 + m;
    int rA = pcol >> 5, cA = pcol & 31;
    #pragma unroll
    for (int tap = 0; tap < 9; ++tap) {
        int kh = tap/3, kw = tap - (tap/3)*3;
        int ii = i0 + rA - 1 + kh;
        int jj = j0 + cA - 1 + kw;
        bool valid = (ii >= 0) && (ii < H_) && (jj >= 0) && (jj < W_);
        int pixA = (rA + 1 + kh)*36 + (cA + 1 + kw);
        half8 a0 = *(const half8*)(halo_c + q*CHS2     + pixA*16);
        half8 a1 = *(const half8*)(halo_c + (q+4)*CHS2 + pixA*16);
        a0 = valid ? a0 : hz;
        a1 = valid ? a1 : hz;
        #pragma unroll
        for (int ks = 0; ks < 2; ++ks) {
            half8 a = ks ? a1 : a0;
            #pragma unroll
            for (int h = 0; h < 2; ++h) {
                half8 bf = *(const half8*)(W0L + (((tap*2+ks)*2+h)<<9) + (lane<<3));
                accA[h] = __builtin_amdgcn_mfma_f32_16x16x32_f16(a, bf, accA[h], 0, 0, 0);
            }
        }
    }
    // epilogue A: D col=m (=oc), row=q*4+r (=pos in wave tile)
    #pragma unroll
    for (int h = 0; h < 2; ++h) {
        int oc = h*16 + m;
        if (oc < 18) {
            float bo = b_off[oc];
            #pragma unroll
            for (int r = 0; r < 4; ++r)
                offL[(w*16 + q*4 + r)*20 + oc] = accA[h][r] + bo;
        }
    }
    __syncthreads();

    // ======== descriptor build: regs first (desc aliases offL), then store ========
    uint4 dreg[3];
    #pragma unroll
    for (int e = 0; e < 3; ++e) {
        int idx = e*256 + t;
        if (idx < 576) {
            int pos = idx / 9;
            int tap = idx - pos*9;
            int kh = tap/3, kw = tap - (tap/3)*3;
            int r = pos >> 5, c = pos & 31;
            float2 o2 = *(const float2*)(offL + pos*20 + 2*tap);
            float py = (float)(i0 + r - 1 + kh) + o2.x;
            float px = (float)(j0 + c - 1 + kw) + o2.y;
            float y0f = floorf(py), x0f = floorf(px);
            float dy = py - y0f, dx = px - x0f;
            int y0 = (int)y0f, x0i = (int)x0f;
            int y1 = y0 + 1,  x1 = x0i + 1;
            bool vy0 = (y0>=0)&(y0<H_),   vy1 = (y1>=0)&(y1<H_);
            bool vx0 = (x0i>=0)&(x0i<W_), vx1 = (x1>=0)&(x1<W_);
            int yc0 = min(max(y0,0),H_-1),  yc1 = min(max(y1,0),H_-1);
            int xc0 = min(max(x0i,0),W_-1), xc1 = min(max(x1,0),W_-1);
            float w00 = (1.f-dy)*(1.f-dx) * ((vy0&&vx0)?1.f:0.f);
            float w01 = (1.f-dy)*dx       * ((vy0&&vx1)?1.f:0.f);
            float w10 = dy*(1.f-dx)       * ((vy1&&vx0)?1.f:0.f);
            float w11 = dy*dx             * ((vy1&&vx1)?1.f:0.f);
            int hy0 = yc0 - (i0-2), hy1 = yc1 - (i0-2);
            int hx0 = xc0 - (j0-2), hx1 = xc1 - (j0-2);
            bool inh = (hy0>=0)&(hy0<6)&(hy1>=0)&(hy1<6)
                     & (hx0>=0)&(hx0<36)&(hx1>=0)&(hx1<36);
            unsigned a0,a1,a2,a3;
            if (inh) { a0 = hy0*36+hx0; a1 = hy0*36+hx1; a2 = hy1*36+hx0; a3 = hy1*36+hx1; }
            else     { a0 = ((yc0<<7)+xc0) | 0x8000u; a1 = (yc0<<7)+xc1;
                       a2 = (yc1<<7)+xc0;             a3 = (yc1<<7)+xc1; }
            __half2 hw0 = __floats2half2_rn(w00, w01);
            __half2 hw1 = __floats2half2_rn(w10, w11);
            dreg[e].x = a0 | (a1 << 16);
            dreg[e].y = a2 | (a3 << 16);
            dreg[e].z = *(unsigned*)&hw0;
            dreg[e].w = *(unsigned*)&hw1;
        }
    }
    __syncthreads();
    #pragma unroll
    for (int e = 0; e < 3; ++e) {
        int idx = e*256 + t;
        if (idx < 576) *(uint4*)(desc + idx*16) = dreg[e];
    }
    __syncthreads();

    // ================= Phase B: own-pos sample + MFMA, barrier-free =================
    floatx4 acc[4];
    #pragma unroll
    for (int og = 0; og < 4; ++og) acc[og] = (floatx4){0.f,0.f,0.f,0.f};

    const char* hq0 = halo_c + q*CHS2;
    const char* hq1 = halo_c + (q+4)*CHS2;
    int mypos = w*16 + m;

    #pragma unroll 3
    for (int tap = 0; tap < 9; ++tap) {
        uint4 d = *(const uint4*)(desc + (mypos*9 + tap)*16);
        unsigned p0i = d.x & 0x7fffu, p1i = d.x >> 16;
        unsigned p2i = d.y & 0xffffu, p3i = d.y >> 16;
        bool inh = (d.x & 0x8000u) == 0u;
        unsigned short b00 = (unsigned short)(d.z & 0xffffu);
        unsigned short b01 = (unsigned short)(d.z >> 16);
        unsigned short b10 = (unsigned short)(d.w & 0xffffu);
        unsigned short b11 = (unsigned short)(d.w >> 16);
        _Float16 h00 = *(_Float16*)&b00, h01 = *(_Float16*)&b01;
        _Float16 h10 = *(_Float16*)&b10, h11 = *(_Float16*)&b11;
        half8 W00 = {h00,h00,h00,h00,h00,h00,h00,h00};
        half8 W01 = {h01,h01,h01,h01,h01,h01,h01,h01};
        half8 W10 = {h10,h10,h10,h10,h10,h10,h10,h10};
        half8 W11 = {h11,h11,h11,h11,h11,h11,h11,h11};
        half8 v00a,v01a,v10a,v11a, v00b,v01b,v10b,v11b;
        if (inh) {
            v00a = *(const half8*)(hq0 + p0i*16);  v00b = *(const half8*)(hq1 + p0i*16);
            v01a = *(const half8*)(hq0 + p1i*16);  v01b = *(const half8*)(hq1 + p1i*16);
            v10a = *(const half8*)(hq0 + p2i*16);  v10b = *(const half8*)(hq1 + p2i*16);
            v11a = *(const half8*)(hq0 + p3i*16);  v11b = *(const half8*)(hq1 + p3i*16);
        } else {
            // rare out-of-halo: scalar f32 NCHW gathers (exec-masked)
            #pragma unroll
            for (int e = 0; e < 8; ++e) {
                v00a[e] = (_Float16)xf[(q*8+e)*HW_ + (int)p0i];
                v00b[e] = (_Float16)xf[((q+4)*8+e)*HW_ + (int)p0i];
                v01a[e] = (_Float16)xf[(q*8+e)*HW_ + (int)p1i];
                v01b[e] = (_Float16)xf[((q+4)*8+e)*HW_ + (int)p1i];
                v10a[e] = (_Float16)xf[(q*8+e)*HW_ + (int)p2i];
                v10b[e] = (_Float16)xf[((q+4)*8+e)*HW_ + (int)p2i];
                v11a[e] = (_Float16)xf[(q*8+e)*HW_ + (int)p3i];
                v11b[e] = (_Float16)xf[((q+4)*8+e)*HW_ + (int)p3i];
            }
        }
        half8 sk0 = v00a*W00 + v01a*W01 + v10a*W10 + v11a*W11;
        half8 sk1 = v00b*W00 + v01b*W01 + v10b*W10 + v11b*W11;
        #pragma unroll
        for (int og = 0; og < 4; ++og) {
            half8 bf0 = *(const half8*)(W2L + (((tap*2+0)*4+og)<<9) + (lane<<3));
            acc[og] = __builtin_amdgcn_mfma_f32_16x16x32_f16(sk0, bf0, acc[og], 0, 0, 0);
            half8 bf1 = *(const half8*)(W2L + (((tap*2+1)*4+og)<<9) + (lane<<3));
            acc[og] = __builtin_amdgcn_mfma_f32_16x16x32_f16(sk1, bf1, acc[og], 0, 0, 0);
        }
    }
    __syncthreads();   // halo dead; epilogue E aliases it

    // epilogue: D col=m -> o=og*16+m, row=q*4+r -> pos=w*16+q*4+r
    float* E = (float*)smem;   // [64 pos][66]
    #pragma unroll
    for (int og = 0; og < 4; ++og) {
        #pragma unroll
        for (int r = 0; r < 4; ++r)
            E[(w*16 + q*4 + r)*66 + og*16 + m] = acc[og][r];
    }
    __syncthreads();
    int obase = (b*64)*HW_ + i0*W_ + j0;
    int orow = (lane >> 5)*W_ + (lane & 31);
    #pragma unroll
    for (int rep = 0; rep < 16; ++rep) {
        int o = rep*4 + w;
        out[obase + o*HW_ + orow] = E[lane*66 + o] + b_dcn[o];
    }
}

extern "C" void kernel_launch(void* const* d_in, const int* in_sizes, int n_in,
                              void* d_out, int out_size, void* d_ws, size_t ws_size,
                              hipStream_t stream) {
    const float* x     = (const float*)d_in[0];
    const float* w_off = (const float*)d_in[1];
    const float* b_off = (const float*)d_in[2];
    const float* w_dcn = (const float*)d_in[3];
    const float* b_dcn = (const float*)d_in[4];
    float* out = (float*)d_out;

    __half* W2L = (__half*)d_ws;                    // 73,728 B
    __half* W0L = (__half*)((char*)d_ws + 73728);   // 36,864 B

    k_prep_w<<<216, 256, 0, stream>>>(w_dcn, w_off, W2L, W0L);
    k_fused<<<1024, 256, 0, stream>>>(x, (const _Float16*)W2L,
                                      (const _Float16*)W0L, b_off, b_dcn, out);
}